// Round 2
// baseline (628.328 us; speedup 1.0000x reference)
//
#include <hip/hip_runtime.h>

// DetectPostProcess: softmax -> decode -> per-(b,c) top-200 -> greedy NMS.
// All DECISIONS (ordering, top-K membership, IoU>0.5) in float64 so they match
// the true-math reference; outputs cast to f32.
// Outputs: objs [B,NC,K,5] then keep [B,NC,K] (as 0.0/1.0), flat in d_out.

constexpr int B = 32;
constexpr int A = 32768;     // power of two
constexpr int ABITS = 15;    // log2(A)
constexpr int NCP1 = 21;
constexpr int NC = 20;
constexpr int K = 200;

#define TH_CONF 0.05
#define TH_IOU  0.5

// ---------------- kernel 1: per-anchor softmax stats: m (f32 max), S (f64 sum) ----
__global__ __launch_bounds__(256) void prep_kernel(
    const float* __restrict__ conf, float* __restrict__ marr,
    double* __restrict__ sarr) {
  int idx = blockIdx.x * 256 + threadIdx.x;   // 0 .. B*A-1
  const float* cp = conf + (size_t)idx * NCP1;
  float x[NCP1];
#pragma unroll
  for (int i = 0; i < NCP1; ++i) x[i] = cp[i];
  float m = x[0];
#pragma unroll
  for (int i = 1; i < NCP1; ++i) m = fmaxf(m, x[i]);
  double S = 0.0;
#pragma unroll
  for (int i = 0; i < NCP1; ++i) S += exp((double)x[i] - (double)m);
  marr[idx] = m;
  sarr[idx] = S;
}

// f64 score of class c at (b,a). If sarr==null, recompute stats inline.
__device__ __forceinline__ double get_sd(const float* __restrict__ conf,
                                         const float* __restrict__ marr,
                                         const double* __restrict__ sarr,
                                         size_t ba, int c) {
  const float* cp = conf + ba * NCP1;
  float m;
  double S;
  if (sarr) {
    m = marr[ba];
    S = sarr[ba];
  } else {
    m = cp[0];
    for (int i = 1; i < NCP1; ++i) m = fmaxf(m, cp[i]);
    S = 0.0;
    for (int i = 0; i < NCP1; ++i) S += exp((double)cp[i] - (double)m);
  }
  return exp((double)cp[c + 1] - (double)m) / S;
}

// f64 box decode for one anchor.
__device__ __forceinline__ void decode_d(const float* __restrict__ loc,
                                         const float* __restrict__ anchor,
                                         size_t ba, int a, double* o) {
  const float* lp = loc + ba * 4;
  const float* ap = anchor + (size_t)a * 4;
  double l0 = lp[0], l1 = lp[1], l2 = lp[2], l3 = lp[3];
  double cx = ap[0], cy = ap[1], aw = ap[2], ah = ap[3];
  double X = (l0 * 0.125) * aw + cx;
  double Y = (l1 * 0.125) * ah + cy;
  double bw = exp(l2 * 0.125) * aw;
  double bh = exp(l3 * 0.125) * ah;
  o[0] = X - bw * 0.5;
  o[1] = Y - bh * 0.5;
  o[2] = X + bw * 0.5;
  o[3] = Y + bh * 0.5;
}

// ---------------- kernel 2: per-(b,c) top-K selection + greedy NMS ----------------
__global__ __launch_bounds__(256) void select_nms_kernel(
    const float* __restrict__ conf, const float* __restrict__ marr,
    const double* __restrict__ sarr, const float* __restrict__ loc,
    const float* __restrict__ anchor, float* __restrict__ out) {
  __shared__ __align__(16) unsigned short s16[A];   // 64 KB radix keys
  __shared__ unsigned hist[256];
  __shared__ unsigned scan0[256];
  __shared__ unsigned long long cand[512];          // (f64 bits & ~0xFFFF) | (65535-a)
  __shared__ unsigned sh_cnt, sh_selbin, sh_need, sh_ctot;

  // overlay (s16 dead after radix/collect passes)
  double* cbd = (double*)s16;                       // [K*4] candidate boxes (f64)
  double* ar = cbd + K * 4;                         // [K]   areas (f64)
  unsigned* rows = (unsigned*)(ar + K);             // [K*8] IoU>TH bitmask rows
  unsigned* kp = rows + K * 8;                      // [K]

  int tid = threadIdx.x;
  int bc = blockIdx.x;
  int b = bc / NC, c = bc % NC;
  size_t base = (size_t)b << ABITS;

  // ---- 1. stage 16-bit keys (0 = below threshold); monotone f64->f32->top16 ----
  for (int a = tid; a < A; a += 256) {
    double sd = get_sd(conf, marr, sarr, base + a, c);
    unsigned short key = 0;
    if (sd >= TH_CONF) {
      float f = (float)sd;
      key = (unsigned short)(__float_as_uint(f) >> 16);
    }
    s16[a] = key;
  }
  __syncthreads();

  // ---- 2. radix-select the 16-bit bucket of the K-th largest key ----
  unsigned need = K, pfx = 0;
  bool smallcase = false;
  for (int p = 0; p < 2; ++p) {
    hist[tid] = 0;
    __syncthreads();
    for (int a = tid; a < A; a += 256) {
      unsigned v = s16[a];
      if (v && (p == 0 || (v >> 8) == pfx))
        atomicAdd(&hist[(p == 0) ? (v >> 8) : (v & 0xFFu)], 1u);
    }
    __syncthreads();
    scan0[tid] = hist[tid];
    __syncthreads();
    for (int st = 1; st < 256; st <<= 1) {   // inclusive suffix sum
      unsigned mine = scan0[tid];
      unsigned oth = (tid + st < 256) ? scan0[tid + st] : 0u;
      __syncthreads();
      scan0[tid] = mine + oth;
      __syncthreads();
    }
    if (p == 0) {
      if (tid == 0) sh_ctot = scan0[0];
      __syncthreads();
      if (sh_ctot <= (unsigned)K) { smallcase = true; break; }
    }
    unsigned nxt = (tid == 255) ? 0u : scan0[tid + 1];
    if (scan0[tid] >= need && nxt < need) { sh_selbin = tid; sh_need = need - nxt; }
    __syncthreads();
    pfx = (pfx << 8) | sh_selbin;
    need = sh_need;
    __syncthreads();
  }
  unsigned pivot16 = smallcase ? 0x3D4Cu : pfx;  // 0x3D4C = bits(0.05f)>>16

  // ---- 3. collect candidates (superset of true top-K) ----
  if (tid == 0) sh_cnt = 0;
  __syncthreads();
  for (int a = tid; a < A; a += 256) {
    double sd = get_sd(conf, marr, sarr, base + a, c);
    if (sd >= TH_CONF) {
      float f = (float)sd;
      if ((__float_as_uint(f) >> 16) >= pivot16) {
        unsigned pos = atomicAdd(&sh_cnt, 1u);
        if (pos < 512) {
          unsigned long long db = (unsigned long long)__double_as_longlong(sd);
          cand[pos] = (db & 0xFFFFFFFFFFFF0000ull) |
                      (unsigned long long)(65535u - (unsigned)a);
        }
      }
    }
  }
  __syncthreads();
  unsigned ccount = sh_cnt < 512u ? sh_cnt : 512u;
  unsigned Ct = ccount < (unsigned)K ? ccount : (unsigned)K;
  for (int i = tid; i < 512; i += 256)
    if ((unsigned)i >= ccount) cand[i] = 0ull;
  __syncthreads();

  // ---- 4. bitonic sort 512 descending: (f64 score bits desc, index asc) ----
  for (unsigned k2 = 2; k2 <= 512; k2 <<= 1) {
    for (unsigned j = k2 >> 1; j > 0; j >>= 1) {
      for (unsigned i = tid; i < 512; i += 256) {
        unsigned ixj = i ^ j;
        if (ixj > i) {
          unsigned long long va = cand[i], vb = cand[ixj];
          bool desc = ((i & k2) == 0);
          if (desc ? (va < vb) : (va > vb)) { cand[i] = vb; cand[ixj] = va; }
        }
      }
      __syncthreads();
    }
  }

  // ---- 5. decode candidate boxes (f64) ----
  if ((unsigned)tid < Ct) {
    unsigned a = 65535u - (unsigned)(cand[tid] & 0xFFFFull);
    double o[4];
    decode_d(loc, anchor, base + a, a, o);
    cbd[tid * 4 + 0] = o[0]; cbd[tid * 4 + 1] = o[1];
    cbd[tid * 4 + 2] = o[2]; cbd[tid * 4 + 3] = o[3];
    ar[tid] = (o[2] - o[0]) * (o[3] - o[1]);
  }
  __syncthreads();

  // ---- 6. IoU bitmask rows: rows[i][w] bit j' => iou(i, w*32+j') > TH ----
  for (int id = tid; id < (int)Ct * 8; id += 256) {
    int i = id >> 3, w = id & 7;
    double xi0 = cbd[i * 4 + 0], yi0 = cbd[i * 4 + 1];
    double xi1 = cbd[i * 4 + 2], yi1 = cbd[i * 4 + 3];
    double ai = ar[i];
    unsigned bits = 0;
    int j0 = w * 32;
    for (int jj = 0; jj < 32; ++jj) {
      int j = j0 + jj;
      if (j < (int)Ct) {
        double ltx = fmax(xi0, cbd[j * 4 + 0]);
        double lty = fmax(yi0, cbd[j * 4 + 1]);
        double rbx = fmin(xi1, cbd[j * 4 + 2]);
        double rby = fmin(yi1, cbd[j * 4 + 3]);
        double iw = fmax(rbx - ltx, 0.0);
        double ih = fmax(rby - lty, 0.0);
        double inter = iw * ih;
        double iou = inter / (ai + ar[j] - inter + 1e-9);
        if (iou > TH_IOU) bits |= (1u << jj);
      }
    }
    rows[i * 8 + w] = bits;
  }
  __syncthreads();

  // ---- 7. greedy scan (wave 0; matches lax.scan semantics) ----
  if (tid < 64) {
    unsigned supp = 0;  // lane w holds suppression bits for indices [w*32, w*32+32)
    for (int i = 0; i < (int)Ct; ++i) {
      unsigned wsrc = __shfl(supp, i >> 5);
      bool kkeep = ((wsrc >> (i & 31)) & 1u) == 0u;
      if (tid == 0) kp[i] = kkeep ? 1u : 0u;
      unsigned rw = (tid < 8) ? rows[i * 8 + tid] : 0u;
      if (kkeep) supp |= rw;
    }
  }
  __syncthreads();

  // ---- 8. write objs + keep ----
  if (tid < K) {
    bool kkeep = ((unsigned)tid < Ct) && (kp[tid] != 0u);
    float o0 = 0.f, o1 = 0.f, o2 = 0.f, o3 = 0.f, o4 = 0.f;
    if (kkeep) {
      o0 = (float)cbd[tid * 4 + 0]; o1 = (float)cbd[tid * 4 + 1];
      o2 = (float)cbd[tid * 4 + 2]; o3 = (float)cbd[tid * 4 + 3];
      double sd = __longlong_as_double(
          (long long)(cand[tid] & 0xFFFFFFFFFFFF0000ull));
      o4 = (float)sd;
    }
    size_t ob = ((size_t)bc * K + tid) * 5;
    out[ob + 0] = o0; out[ob + 1] = o1; out[ob + 2] = o2;
    out[ob + 3] = o3; out[ob + 4] = o4;
    out[(size_t)B * NC * K * 5 + (size_t)bc * K + tid] = kkeep ? 1.f : 0.f;
  }
}

extern "C" void kernel_launch(void* const* d_in, const int* in_sizes, int n_in,
                              void* d_out, int out_size, void* d_ws, size_t ws_size,
                              hipStream_t stream) {
  (void)in_sizes; (void)n_in; (void)out_size;
  const float* conf = (const float*)d_in[0];
  const float* loc = (const float*)d_in[1];
  const float* anchor = (const float*)d_in[2];
  float* out = (float*)d_out;

  size_t need = (size_t)B * A * (sizeof(float) + sizeof(double));  // 12 MB
  float* marr = nullptr;
  double* sarr = nullptr;
  if (ws_size >= need) {
    marr = (float*)d_ws;
    sarr = (double*)((char*)d_ws + (size_t)B * A * sizeof(float));
    prep_kernel<<<(B * A) / 256, 256, 0, stream>>>(conf, marr, sarr);
  }
  select_nms_kernel<<<B * NC, 256, 0, stream>>>(conf, marr, sarr, loc, anchor, out);
}

// Round 3
// 257.990 us; speedup vs baseline: 2.4355x; 2.4355x over previous
//
#include <hip/hip_runtime.h>

// DetectPostProcess: softmax -> decode -> per-(b,c) top-200 -> greedy NMS.
// Decisions (ordering, top-K membership, IoU>0.5) in f64, bit-identical to the
// round-2 passing kernel; 16-bit selection keys precomputed in prep (fast path).
// Outputs: objs [B,NC,K,5] then keep [B,NC,K] (as 0.0/1.0), flat in d_out.

constexpr int B = 32;
constexpr int A = 32768;     // power of two
constexpr int ABITS = 15;    // log2(A)
constexpr int NCP1 = 21;
constexpr int NC = 20;
constexpr int K = 200;

#define TH_CONF 0.05
#define TH_IOU  0.5

// ============================ FAST PATH =====================================
// prep_fast: per (b,a): m (f32 max), S (f64 sum), and 20 transposed u16 keys.
__global__ __launch_bounds__(256) void prep_fast(
    const float* __restrict__ conf, float* __restrict__ marr,
    double* __restrict__ sarr, unsigned short* __restrict__ keys) {
  int idx = blockIdx.x * 256 + threadIdx.x;   // 0 .. B*A-1
  int b = idx >> ABITS;
  int a = idx & (A - 1);
  const float* cp = conf + (size_t)idx * NCP1;
  float x[NCP1];
#pragma unroll
  for (int i = 0; i < NCP1; ++i) x[i] = cp[i];
  float m = x[0];
#pragma unroll
  for (int i = 1; i < NCP1; ++i) m = fmaxf(m, x[i]);
  double e[NCP1];
  double S = 0.0;
#pragma unroll
  for (int i = 0; i < NCP1; ++i) {
    e[i] = exp((double)x[i] - (double)m);
    S += e[i];
  }
  marr[idx] = m;
  sarr[idx] = S;
  double rs = 1.0 / S;
  size_t kbase = ((size_t)(b * NC) << ABITS) + a;
#pragma unroll
  for (int c = 0; c < NC; ++c) {
    double sd = e[c + 1] * rs;                 // ~1ulp from e/S; key-grade only
    unsigned short key = 0;
    if (sd >= TH_CONF) {
      float f = (float)sd;
      key = (unsigned short)(__float_as_uint(f) >> 16);
    }
    keys[kbase + ((size_t)c << ABITS)] = key;
  }
}

// f64 box decode for one anchor.
__device__ __forceinline__ void decode_d(const float* __restrict__ loc,
                                         const float* __restrict__ anchor,
                                         size_t ba, int a, double* o) {
  const float* lp = loc + ba * 4;
  const float* ap = anchor + (size_t)a * 4;
  double l0 = lp[0], l1 = lp[1], l2 = lp[2], l3 = lp[3];
  double cx = ap[0], cy = ap[1], aw = ap[2], ah = ap[3];
  double X = (l0 * 0.125) * aw + cx;
  double Y = (l1 * 0.125) * ah + cy;
  double bw = exp(l2 * 0.125) * aw;
  double bh = exp(l3 * 0.125) * ah;
  o[0] = X - bw * 0.5;
  o[1] = Y - bh * 0.5;
  o[2] = X + bw * 0.5;
  o[3] = Y + bh * 0.5;
}

// select_fast: radix-select on global key row, exact f64 for candidates only.
__global__ __launch_bounds__(256) void select_fast(
    const float* __restrict__ conf, const float* __restrict__ marr,
    const double* __restrict__ sarr, const float* __restrict__ loc,
    const float* __restrict__ anchor, const unsigned short* __restrict__ keys,
    float* __restrict__ out) {
  __shared__ unsigned hist[256];
  __shared__ unsigned scan0[256];
  __shared__ unsigned long long cand[512];
  __shared__ int clist[512];
  __shared__ double cbd[K * 4];
  __shared__ double ar[K];
  __shared__ unsigned rows[K * 8];
  __shared__ unsigned kp[K];
  __shared__ unsigned sh_cnt, sh_selbin, sh_need, sh_ctot;

  int tid = threadIdx.x;
  int bc = blockIdx.x;
  int b = bc / NC, c = bc % NC;
  size_t base = (size_t)b << ABITS;
  const unsigned short* krow = keys + ((size_t)bc << ABITS);

  // ---- 1. radix-select the 16-bit bucket of the K-th largest key ----
  unsigned need = K, pfx = 0;
  bool smallcase = false;
  for (int p = 0; p < 2; ++p) {
    hist[tid] = 0;
    __syncthreads();
    for (int a = tid; a < A; a += 256) {
      unsigned v = krow[a];
      if (v && (p == 0 || (v >> 8) == pfx))
        atomicAdd(&hist[(p == 0) ? (v >> 8) : (v & 0xFFu)], 1u);
    }
    __syncthreads();
    scan0[tid] = hist[tid];
    __syncthreads();
    for (int st = 1; st < 256; st <<= 1) {   // inclusive suffix sum
      unsigned mine = scan0[tid];
      unsigned oth = (tid + st < 256) ? scan0[tid + st] : 0u;
      __syncthreads();
      scan0[tid] = mine + oth;
      __syncthreads();
    }
    if (p == 0) {
      if (tid == 0) sh_ctot = scan0[0];
      __syncthreads();
      if (sh_ctot <= (unsigned)K) { smallcase = true; break; }
    }
    unsigned nxt = (tid == 255) ? 0u : scan0[tid + 1];
    if (scan0[tid] >= need && nxt < need) { sh_selbin = tid; sh_need = need - nxt; }
    __syncthreads();
    pfx = (pfx << 8) | sh_selbin;
    need = sh_need;
    __syncthreads();
  }
  unsigned pivot16 = smallcase ? 0x3D4Cu : pfx;  // 0x3D4C = bits(0.05f)>>16

  // ---- 2. collect candidate anchor ids (superset of true top-K) ----
  if (tid == 0) sh_cnt = 0;
  __syncthreads();
  for (int a = tid; a < A; a += 256) {
    unsigned v = krow[a];
    if (v && v >= pivot16) {
      unsigned pos = atomicAdd(&sh_cnt, 1u);
      if (pos < 512) clist[pos] = a;
    }
  }
  __syncthreads();
  unsigned ccount = sh_cnt < 512u ? sh_cnt : 512u;
  unsigned Ct = ccount < (unsigned)K ? ccount : (unsigned)K;

  // ---- 3. exact f64 scores for candidates; build sort keys ----
  for (int i = tid; i < 512; i += 256) {
    unsigned long long key = 0ull;
    if ((unsigned)i < ccount) {
      int a = clist[i];
      size_t ba = base + a;
      double sd = exp((double)conf[ba * NCP1 + (c + 1)] - (double)marr[ba]) / sarr[ba];
      if (sd >= TH_CONF) {
        unsigned long long db = (unsigned long long)__double_as_longlong(sd);
        key = (db & 0xFFFFFFFFFFFF0000ull) |
              (unsigned long long)(65535u - (unsigned)a);
      }
    }
    cand[i] = key;
  }
  __syncthreads();

  // ---- 4. bitonic sort 512 descending: (f64 score bits desc, index asc) ----
  for (unsigned k2 = 2; k2 <= 512; k2 <<= 1) {
    for (unsigned j = k2 >> 1; j > 0; j >>= 1) {
      for (unsigned i = tid; i < 512; i += 256) {
        unsigned ixj = i ^ j;
        if (ixj > i) {
          unsigned long long va = cand[i], vb = cand[ixj];
          bool desc = ((i & k2) == 0);
          if (desc ? (va < vb) : (va > vb)) { cand[i] = vb; cand[ixj] = va; }
        }
      }
      __syncthreads();
    }
  }

  // ---- 5. decode candidate boxes (f64) ----
  if ((unsigned)tid < Ct) {
    unsigned long long key = cand[tid];
    bool valid = (key >> 16) != 0ull;
    double o[4] = {0.0, 0.0, 0.0, 0.0};
    double aa = 0.0;
    if (valid) {
      unsigned a = (65535u - (unsigned)(key & 0xFFFFull)) & (A - 1);
      decode_d(loc, anchor, base + a, a, o);
      aa = (o[2] - o[0]) * (o[3] - o[1]);
    }
    cbd[tid * 4 + 0] = o[0]; cbd[tid * 4 + 1] = o[1];
    cbd[tid * 4 + 2] = o[2]; cbd[tid * 4 + 3] = o[3];
    ar[tid] = aa;
  }
  __syncthreads();

  // ---- 6. IoU bitmask rows: rows[i][w] bit j' => iou(i, w*32+j') > TH ----
  for (int id = tid; id < (int)Ct * 8; id += 256) {
    int i = id >> 3, w = id & 7;
    double xi0 = cbd[i * 4 + 0], yi0 = cbd[i * 4 + 1];
    double xi1 = cbd[i * 4 + 2], yi1 = cbd[i * 4 + 3];
    double ai = ar[i];
    unsigned bits = 0;
    int j0 = w * 32;
    for (int jj = 0; jj < 32; ++jj) {
      int j = j0 + jj;
      if (j < (int)Ct) {
        double ltx = fmax(xi0, cbd[j * 4 + 0]);
        double lty = fmax(yi0, cbd[j * 4 + 1]);
        double rbx = fmin(xi1, cbd[j * 4 + 2]);
        double rby = fmin(yi1, cbd[j * 4 + 3]);
        double iw = fmax(rbx - ltx, 0.0);
        double ih = fmax(rby - lty, 0.0);
        double inter = iw * ih;
        double iou = inter / (ai + ar[j] - inter + 1e-9);
        if (iou > TH_IOU) bits |= (1u << jj);
      }
    }
    rows[i * 8 + w] = bits;
  }
  __syncthreads();

  // ---- 7. greedy scan (wave 0; matches lax.scan semantics) ----
  if (tid < 64) {
    unsigned supp = 0;
    for (int i = 0; i < (int)Ct; ++i) {
      unsigned wsrc = __shfl(supp, i >> 5);
      bool kkeep = ((wsrc >> (i & 31)) & 1u) == 0u;
      if (tid == 0) kp[i] = kkeep ? 1u : 0u;
      unsigned rw = (tid < 8) ? rows[i * 8 + tid] : 0u;
      if (kkeep) supp |= rw;
    }
  }
  __syncthreads();

  // ---- 8. write objs + keep ----
  if (tid < K) {
    bool kkeep = ((unsigned)tid < Ct) && (kp[tid] != 0u) && ((cand[tid] >> 16) != 0ull);
    float o0 = 0.f, o1 = 0.f, o2 = 0.f, o3 = 0.f, o4 = 0.f;
    if (kkeep) {
      o0 = (float)cbd[tid * 4 + 0]; o1 = (float)cbd[tid * 4 + 1];
      o2 = (float)cbd[tid * 4 + 2]; o3 = (float)cbd[tid * 4 + 3];
      double sd = __longlong_as_double(
          (long long)(cand[tid] & 0xFFFFFFFFFFFF0000ull));
      o4 = (float)sd;
    }
    size_t ob = ((size_t)bc * K + tid) * 5;
    out[ob + 0] = o0; out[ob + 1] = o1; out[ob + 2] = o2;
    out[ob + 3] = o3; out[ob + 4] = o4;
    out[(size_t)B * NC * K * 5 + (size_t)bc * K + tid] = kkeep ? 1.f : 0.f;
  }
}

// ============================ FALLBACK PATH (round-2, passing) ==============
__global__ __launch_bounds__(256) void prep_kernel(
    const float* __restrict__ conf, float* __restrict__ marr,
    double* __restrict__ sarr) {
  int idx = blockIdx.x * 256 + threadIdx.x;
  const float* cp = conf + (size_t)idx * NCP1;
  float x[NCP1];
#pragma unroll
  for (int i = 0; i < NCP1; ++i) x[i] = cp[i];
  float m = x[0];
#pragma unroll
  for (int i = 1; i < NCP1; ++i) m = fmaxf(m, x[i]);
  double S = 0.0;
#pragma unroll
  for (int i = 0; i < NCP1; ++i) S += exp((double)x[i] - (double)m);
  marr[idx] = m;
  sarr[idx] = S;
}

__device__ __forceinline__ double get_sd(const float* __restrict__ conf,
                                         const float* __restrict__ marr,
                                         const double* __restrict__ sarr,
                                         size_t ba, int c) {
  const float* cp = conf + ba * NCP1;
  float m;
  double S;
  if (sarr) {
    m = marr[ba];
    S = sarr[ba];
  } else {
    m = cp[0];
    for (int i = 1; i < NCP1; ++i) m = fmaxf(m, cp[i]);
    S = 0.0;
    for (int i = 0; i < NCP1; ++i) S += exp((double)cp[i] - (double)m);
  }
  return exp((double)cp[c + 1] - (double)m) / S;
}

__global__ __launch_bounds__(256) void select_nms_kernel(
    const float* __restrict__ conf, const float* __restrict__ marr,
    const double* __restrict__ sarr, const float* __restrict__ loc,
    const float* __restrict__ anchor, float* __restrict__ out) {
  __shared__ __align__(16) unsigned short s16[A];
  __shared__ unsigned hist[256];
  __shared__ unsigned scan0[256];
  __shared__ unsigned long long cand[512];
  __shared__ unsigned sh_cnt, sh_selbin, sh_need, sh_ctot;

  double* cbd = (double*)s16;
  double* ar = cbd + K * 4;
  unsigned* rows = (unsigned*)(ar + K);
  unsigned* kp = rows + K * 8;

  int tid = threadIdx.x;
  int bc = blockIdx.x;
  int b = bc / NC, c = bc % NC;
  size_t base = (size_t)b << ABITS;

  for (int a = tid; a < A; a += 256) {
    double sd = get_sd(conf, marr, sarr, base + a, c);
    unsigned short key = 0;
    if (sd >= TH_CONF) {
      float f = (float)sd;
      key = (unsigned short)(__float_as_uint(f) >> 16);
    }
    s16[a] = key;
  }
  __syncthreads();

  unsigned need = K, pfx = 0;
  bool smallcase = false;
  for (int p = 0; p < 2; ++p) {
    hist[tid] = 0;
    __syncthreads();
    for (int a = tid; a < A; a += 256) {
      unsigned v = s16[a];
      if (v && (p == 0 || (v >> 8) == pfx))
        atomicAdd(&hist[(p == 0) ? (v >> 8) : (v & 0xFFu)], 1u);
    }
    __syncthreads();
    scan0[tid] = hist[tid];
    __syncthreads();
    for (int st = 1; st < 256; st <<= 1) {
      unsigned mine = scan0[tid];
      unsigned oth = (tid + st < 256) ? scan0[tid + st] : 0u;
      __syncthreads();
      scan0[tid] = mine + oth;
      __syncthreads();
    }
    if (p == 0) {
      if (tid == 0) sh_ctot = scan0[0];
      __syncthreads();
      if (sh_ctot <= (unsigned)K) { smallcase = true; break; }
    }
    unsigned nxt = (tid == 255) ? 0u : scan0[tid + 1];
    if (scan0[tid] >= need && nxt < need) { sh_selbin = tid; sh_need = need - nxt; }
    __syncthreads();
    pfx = (pfx << 8) | sh_selbin;
    need = sh_need;
    __syncthreads();
  }
  unsigned pivot16 = smallcase ? 0x3D4Cu : pfx;

  if (tid == 0) sh_cnt = 0;
  __syncthreads();
  for (int a = tid; a < A; a += 256) {
    double sd = get_sd(conf, marr, sarr, base + a, c);
    if (sd >= TH_CONF) {
      float f = (float)sd;
      if ((__float_as_uint(f) >> 16) >= pivot16) {
        unsigned pos = atomicAdd(&sh_cnt, 1u);
        if (pos < 512) {
          unsigned long long db = (unsigned long long)__double_as_longlong(sd);
          cand[pos] = (db & 0xFFFFFFFFFFFF0000ull) |
                      (unsigned long long)(65535u - (unsigned)a);
        }
      }
    }
  }
  __syncthreads();
  unsigned ccount = sh_cnt < 512u ? sh_cnt : 512u;
  unsigned Ct = ccount < (unsigned)K ? ccount : (unsigned)K;
  for (int i = tid; i < 512; i += 256)
    if ((unsigned)i >= ccount) cand[i] = 0ull;
  __syncthreads();

  for (unsigned k2 = 2; k2 <= 512; k2 <<= 1) {
    for (unsigned j = k2 >> 1; j > 0; j >>= 1) {
      for (unsigned i = tid; i < 512; i += 256) {
        unsigned ixj = i ^ j;
        if (ixj > i) {
          unsigned long long va = cand[i], vb = cand[ixj];
          bool desc = ((i & k2) == 0);
          if (desc ? (va < vb) : (va > vb)) { cand[i] = vb; cand[ixj] = va; }
        }
      }
      __syncthreads();
    }
  }

  if ((unsigned)tid < Ct) {
    unsigned a = 65535u - (unsigned)(cand[tid] & 0xFFFFull);
    double o[4];
    decode_d(loc, anchor, base + a, a, o);
    cbd[tid * 4 + 0] = o[0]; cbd[tid * 4 + 1] = o[1];
    cbd[tid * 4 + 2] = o[2]; cbd[tid * 4 + 3] = o[3];
    ar[tid] = (o[2] - o[0]) * (o[3] - o[1]);
  }
  __syncthreads();

  for (int id = tid; id < (int)Ct * 8; id += 256) {
    int i = id >> 3, w = id & 7;
    double xi0 = cbd[i * 4 + 0], yi0 = cbd[i * 4 + 1];
    double xi1 = cbd[i * 4 + 2], yi1 = cbd[i * 4 + 3];
    double ai = ar[i];
    unsigned bits = 0;
    int j0 = w * 32;
    for (int jj = 0; jj < 32; ++jj) {
      int j = j0 + jj;
      if (j < (int)Ct) {
        double ltx = fmax(xi0, cbd[j * 4 + 0]);
        double lty = fmax(yi0, cbd[j * 4 + 1]);
        double rbx = fmin(xi1, cbd[j * 4 + 2]);
        double rby = fmin(yi1, cbd[j * 4 + 3]);
        double iw = fmax(rbx - ltx, 0.0);
        double ih = fmax(rby - lty, 0.0);
        double inter = iw * ih;
        double iou = inter / (ai + ar[j] - inter + 1e-9);
        if (iou > TH_IOU) bits |= (1u << jj);
      }
    }
    rows[i * 8 + w] = bits;
  }
  __syncthreads();

  if (tid < 64) {
    unsigned supp = 0;
    for (int i = 0; i < (int)Ct; ++i) {
      unsigned wsrc = __shfl(supp, i >> 5);
      bool kkeep = ((wsrc >> (i & 31)) & 1u) == 0u;
      if (tid == 0) kp[i] = kkeep ? 1u : 0u;
      unsigned rw = (tid < 8) ? rows[i * 8 + tid] : 0u;
      if (kkeep) supp |= rw;
    }
  }
  __syncthreads();

  if (tid < K) {
    bool kkeep = ((unsigned)tid < Ct) && (kp[tid] != 0u);
    float o0 = 0.f, o1 = 0.f, o2 = 0.f, o3 = 0.f, o4 = 0.f;
    if (kkeep) {
      o0 = (float)cbd[tid * 4 + 0]; o1 = (float)cbd[tid * 4 + 1];
      o2 = (float)cbd[tid * 4 + 2]; o3 = (float)cbd[tid * 4 + 3];
      double sd = __longlong_as_double(
          (long long)(cand[tid] & 0xFFFFFFFFFFFF0000ull));
      o4 = (float)sd;
    }
    size_t ob = ((size_t)bc * K + tid) * 5;
    out[ob + 0] = o0; out[ob + 1] = o1; out[ob + 2] = o2;
    out[ob + 3] = o3; out[ob + 4] = o4;
    out[(size_t)B * NC * K * 5 + (size_t)bc * K + tid] = kkeep ? 1.f : 0.f;
  }
}

extern "C" void kernel_launch(void* const* d_in, const int* in_sizes, int n_in,
                              void* d_out, int out_size, void* d_ws, size_t ws_size,
                              hipStream_t stream) {
  (void)in_sizes; (void)n_in; (void)out_size;
  const float* conf = (const float*)d_in[0];
  const float* loc = (const float*)d_in[1];
  const float* anchor = (const float*)d_in[2];
  float* out = (float*)d_out;

  size_t nBA = (size_t)B * A;
  size_t need_fast = nBA * sizeof(double) + nBA * sizeof(float) +
                     nBA * NC * sizeof(unsigned short);      // 52 MB
  size_t need_mid = nBA * (sizeof(float) + sizeof(double));  // 12 MB

  if (ws_size >= need_fast) {
    double* sarr = (double*)d_ws;
    float* marr = (float*)(sarr + nBA);
    unsigned short* keys = (unsigned short*)(marr + nBA);
    prep_fast<<<(B * A) / 256, 256, 0, stream>>>(conf, marr, sarr, keys);
    select_fast<<<B * NC, 256, 0, stream>>>(conf, marr, sarr, loc, anchor, keys, out);
  } else if (ws_size >= need_mid) {
    float* marr = (float*)d_ws;
    double* sarr = (double*)((char*)d_ws + nBA * sizeof(float));
    prep_kernel<<<(B * A) / 256, 256, 0, stream>>>(conf, marr, sarr);
    select_nms_kernel<<<B * NC, 256, 0, stream>>>(conf, marr, sarr, loc, anchor, out);
  } else {
    select_nms_kernel<<<B * NC, 256, 0, stream>>>(conf, nullptr, nullptr, loc, anchor, out);
  }
}

// Round 4
// 157.093 us; speedup vs baseline: 3.9997x; 1.6423x over previous
//
#include <hip/hip_runtime.h>

// DetectPostProcess: softmax -> decode -> per-(b,c) top-200 -> greedy NMS.
// Decisions (ordering, top-K membership, IoU>0.5) in f64, identical to the
// round-2/3 passing kernels; 16-bit selection keys precomputed in prep.
// Round 4: single-pass range-compressed histogram (1024 bins over the
// reachable key range [0x3D4C, 0x3F80)) + uint4-vectorized key passes.
// Outputs: objs [B,NC,K,5] then keep [B,NC,K] (as 0.0/1.0), flat in d_out.

constexpr int B = 32;
constexpr int A = 32768;     // power of two
constexpr int ABITS = 15;    // log2(A)
constexpr int NCP1 = 21;
constexpr int NC = 20;
constexpr int K = 200;

#define TH_CONF 0.05
#define TH_IOU  0.5

// ============================ FAST PATH =====================================
// prep_fast: per (b,a): m (f32 max), S (f64 sum), and 20 transposed u16 keys.
__global__ __launch_bounds__(256) void prep_fast(
    const float* __restrict__ conf, float* __restrict__ marr,
    double* __restrict__ sarr, unsigned short* __restrict__ keys) {
  int idx = blockIdx.x * 256 + threadIdx.x;   // 0 .. B*A-1
  int b = idx >> ABITS;
  int a = idx & (A - 1);
  const float* cp = conf + (size_t)idx * NCP1;
  float x[NCP1];
#pragma unroll
  for (int i = 0; i < NCP1; ++i) x[i] = cp[i];
  float m = x[0];
#pragma unroll
  for (int i = 1; i < NCP1; ++i) m = fmaxf(m, x[i]);
  double e[NCP1];
  double S = 0.0;
#pragma unroll
  for (int i = 0; i < NCP1; ++i) {
    e[i] = exp((double)x[i] - (double)m);
    S += e[i];
  }
  marr[idx] = m;
  sarr[idx] = S;
  double rs = 1.0 / S;
  size_t kbase = ((size_t)(b * NC) << ABITS) + a;
#pragma unroll
  for (int c = 0; c < NC; ++c) {
    double sd = e[c + 1] * rs;                 // ~1ulp from e/S; key-grade only
    unsigned short key = 0;
    if (sd >= TH_CONF) {
      float f = (float)sd;
      key = (unsigned short)(__float_as_uint(f) >> 16);
    }
    keys[kbase + ((size_t)c << ABITS)] = key;
  }
}

// f64 box decode for one anchor.
__device__ __forceinline__ void decode_d(const float* __restrict__ loc,
                                         const float* __restrict__ anchor,
                                         size_t ba, int a, double* o) {
  const float* lp = loc + ba * 4;
  const float* ap = anchor + (size_t)a * 4;
  double l0 = lp[0], l1 = lp[1], l2 = lp[2], l3 = lp[3];
  double cx = ap[0], cy = ap[1], aw = ap[2], ah = ap[3];
  double X = (l0 * 0.125) * aw + cx;
  double Y = (l1 * 0.125) * ah + cy;
  double bw = exp(l2 * 0.125) * aw;
  double bh = exp(l3 * 0.125) * ah;
  o[0] = X - bw * 0.5;
  o[1] = Y - bh * 0.5;
  o[2] = X + bw * 0.5;
  o[3] = Y + bh * 0.5;
}

// select_fast: single-pass pivot histogram + vectorized collect; exact f64 for
// candidates only; sort + IoU + greedy scan as in the passing round-3 kernel.
__global__ __launch_bounds__(256) void select_fast(
    const float* __restrict__ conf, const float* __restrict__ marr,
    const double* __restrict__ sarr, const float* __restrict__ loc,
    const float* __restrict__ anchor, const unsigned short* __restrict__ keys,
    float* __restrict__ out) {
  constexpr int NBIN = 1024;
  constexpr unsigned KBASE = 0x3D4Cu;   // bits(0.05f) >> 16; min nonzero key

  __shared__ unsigned hist[NBIN];
  __shared__ unsigned wsum[256];
  __shared__ unsigned long long cand[512];
  __shared__ int clist[512];
  __shared__ double cbd[K * 4];
  __shared__ double ar[K];
  __shared__ unsigned rows[K * 8];
  __shared__ unsigned kp[K];
  __shared__ unsigned sh_cnt, sh_selbin, sh_total;

  int tid = threadIdx.x;
  int bc = blockIdx.x;
  int b = bc / NC, c = bc % NC;
  size_t base = (size_t)b << ABITS;
  const unsigned short* krow = keys + ((size_t)bc << ABITS);
  const uint4* kv = (const uint4*)krow;     // A/8 vec entries (8 keys each)

  // ---- 1. one-pass histogram over compressed key range ----
  for (int i = tid; i < NBIN; i += 256) hist[i] = 0;
  if (tid == 0) sh_cnt = 0;
  __syncthreads();
  for (int i = tid; i < A / 8; i += 256) {
    uint4 v = kv[i];
    unsigned w[4] = {v.x, v.y, v.z, v.w};
#pragma unroll
    for (int q = 0; q < 4; ++q) {
      unsigned lo = w[q] & 0xFFFFu, hi = w[q] >> 16;
      if (lo) atomicAdd(&hist[min(lo - KBASE, (unsigned)(NBIN - 1))], 1u);
      if (hi) atomicAdd(&hist[min(hi - KBASE, (unsigned)(NBIN - 1))], 1u);
    }
  }
  __syncthreads();

  // ---- 2. suffix scan (cnt_ge) + exact 16-bit pivot ----
  unsigned h0 = hist[tid * 4 + 0], h1 = hist[tid * 4 + 1];
  unsigned h2 = hist[tid * 4 + 2], h3 = hist[tid * 4 + 3];
  wsum[tid] = h0 + h1 + h2 + h3;
  __syncthreads();
  for (int st = 1; st < 256; st <<= 1) {   // inclusive suffix sum over threads
    unsigned mine = wsum[tid];
    unsigned oth = (tid + st < 256) ? wsum[tid + st] : 0u;
    __syncthreads();
    wsum[tid] = mine + oth;
    __syncthreads();
  }
  unsigned above = (tid < 255) ? wsum[tid + 1] : 0u;  // cnt_ge at bin 4*(tid+1)
  if (tid == 0) sh_total = wsum[0];
  unsigned cg3 = h3 + above;
  unsigned cg2 = h2 + cg3;
  unsigned cg1 = h1 + cg2;
  unsigned cg0 = h0 + cg1;
  if (cg3 >= (unsigned)K && above < (unsigned)K) sh_selbin = tid * 4 + 3;
  if (cg2 >= (unsigned)K && cg3 < (unsigned)K) sh_selbin = tid * 4 + 2;
  if (cg1 >= (unsigned)K && cg2 < (unsigned)K) sh_selbin = tid * 4 + 1;
  if (cg0 >= (unsigned)K && cg1 < (unsigned)K) sh_selbin = tid * 4 + 0;
  __syncthreads();
  unsigned pivot16 = (sh_total <= (unsigned)K) ? KBASE : (KBASE + sh_selbin);

  // ---- 3. collect candidate anchor ids (superset of true top-K) ----
  for (int i = tid; i < A / 8; i += 256) {
    uint4 v = kv[i];
    unsigned w[4] = {v.x, v.y, v.z, v.w};
#pragma unroll
    for (int q = 0; q < 4; ++q) {
      unsigned lo = w[q] & 0xFFFFu, hi = w[q] >> 16;
      if (lo >= pivot16) {
        unsigned pos = atomicAdd(&sh_cnt, 1u);
        if (pos < 512) clist[pos] = i * 8 + q * 2 + 0;
      }
      if (hi >= pivot16) {
        unsigned pos = atomicAdd(&sh_cnt, 1u);
        if (pos < 512) clist[pos] = i * 8 + q * 2 + 1;
      }
    }
  }
  __syncthreads();
  unsigned ccount = sh_cnt < 512u ? sh_cnt : 512u;
  unsigned Ct = ccount < (unsigned)K ? ccount : (unsigned)K;

  // ---- 4. exact f64 scores for candidates; build sort keys ----
  for (int i = tid; i < 512; i += 256) {
    unsigned long long key = 0ull;
    if ((unsigned)i < ccount) {
      int a = clist[i];
      size_t ba = base + a;
      double sd = exp((double)conf[ba * NCP1 + (c + 1)] - (double)marr[ba]) / sarr[ba];
      if (sd >= TH_CONF) {
        unsigned long long db = (unsigned long long)__double_as_longlong(sd);
        key = (db & 0xFFFFFFFFFFFF0000ull) |
              (unsigned long long)(65535u - (unsigned)a);
      }
    }
    cand[i] = key;
  }
  __syncthreads();

  // ---- 5. bitonic sort (adaptive 256/512) desc: (score bits desc, idx asc) ----
  unsigned n2 = (ccount <= 256u) ? 256u : 512u;
  for (unsigned k2 = 2; k2 <= n2; k2 <<= 1) {
    for (unsigned j = k2 >> 1; j > 0; j >>= 1) {
      for (unsigned i = tid; i < n2; i += 256) {
        unsigned ixj = i ^ j;
        if (ixj > i) {
          unsigned long long va = cand[i], vb = cand[ixj];
          bool desc = ((i & k2) == 0);
          if (desc ? (va < vb) : (va > vb)) { cand[i] = vb; cand[ixj] = va; }
        }
      }
      __syncthreads();
    }
  }

  // ---- 6. decode candidate boxes (f64) ----
  if ((unsigned)tid < Ct) {
    unsigned long long key = cand[tid];
    bool valid = (key >> 16) != 0ull;
    double o[4] = {0.0, 0.0, 0.0, 0.0};
    double aa = 0.0;
    if (valid) {
      unsigned a = (65535u - (unsigned)(key & 0xFFFFull)) & (A - 1);
      decode_d(loc, anchor, base + a, a, o);
      aa = (o[2] - o[0]) * (o[3] - o[1]);
    }
    cbd[tid * 4 + 0] = o[0]; cbd[tid * 4 + 1] = o[1];
    cbd[tid * 4 + 2] = o[2]; cbd[tid * 4 + 3] = o[3];
    ar[tid] = aa;
  }
  __syncthreads();

  // ---- 7. IoU bitmask rows: rows[i][w] bit j' => iou(i, w*32+j') > TH ----
  for (int id = tid; id < (int)Ct * 8; id += 256) {
    int i = id >> 3, w = id & 7;
    double xi0 = cbd[i * 4 + 0], yi0 = cbd[i * 4 + 1];
    double xi1 = cbd[i * 4 + 2], yi1 = cbd[i * 4 + 3];
    double ai = ar[i];
    unsigned bits = 0;
    int j0 = w * 32;
    for (int jj = 0; jj < 32; ++jj) {
      int j = j0 + jj;
      if (j < (int)Ct) {
        double ltx = fmax(xi0, cbd[j * 4 + 0]);
        double lty = fmax(yi0, cbd[j * 4 + 1]);
        double rbx = fmin(xi1, cbd[j * 4 + 2]);
        double rby = fmin(yi1, cbd[j * 4 + 3]);
        double iw = fmax(rbx - ltx, 0.0);
        double ih = fmax(rby - lty, 0.0);
        double inter = iw * ih;
        double iou = inter / (ai + ar[j] - inter + 1e-9);
        if (iou > TH_IOU) bits |= (1u << jj);
      }
    }
    rows[i * 8 + w] = bits;
  }
  __syncthreads();

  // ---- 8. greedy scan (wave 0; matches lax.scan semantics) ----
  if (tid < 64) {
    unsigned supp = 0;
    for (int i = 0; i < (int)Ct; ++i) {
      unsigned wsrc = __shfl(supp, i >> 5);
      bool kkeep = ((wsrc >> (i & 31)) & 1u) == 0u;
      if (tid == 0) kp[i] = kkeep ? 1u : 0u;
      unsigned rw = (tid < 8) ? rows[i * 8 + tid] : 0u;
      if (kkeep) supp |= rw;
    }
  }
  __syncthreads();

  // ---- 9. write objs + keep ----
  if (tid < K) {
    bool kkeep = ((unsigned)tid < Ct) && (kp[tid] != 0u) && ((cand[tid] >> 16) != 0ull);
    float o0 = 0.f, o1 = 0.f, o2 = 0.f, o3 = 0.f, o4 = 0.f;
    if (kkeep) {
      o0 = (float)cbd[tid * 4 + 0]; o1 = (float)cbd[tid * 4 + 1];
      o2 = (float)cbd[tid * 4 + 2]; o3 = (float)cbd[tid * 4 + 3];
      double sd = __longlong_as_double(
          (long long)(cand[tid] & 0xFFFFFFFFFFFF0000ull));
      o4 = (float)sd;
    }
    size_t ob = ((size_t)bc * K + tid) * 5;
    out[ob + 0] = o0; out[ob + 1] = o1; out[ob + 2] = o2;
    out[ob + 3] = o3; out[ob + 4] = o4;
    out[(size_t)B * NC * K * 5 + (size_t)bc * K + tid] = kkeep ? 1.f : 0.f;
  }
}

// ============================ FALLBACK PATH (round-2, passing) ==============
__global__ __launch_bounds__(256) void prep_kernel(
    const float* __restrict__ conf, float* __restrict__ marr,
    double* __restrict__ sarr) {
  int idx = blockIdx.x * 256 + threadIdx.x;
  const float* cp = conf + (size_t)idx * NCP1;
  float x[NCP1];
#pragma unroll
  for (int i = 0; i < NCP1; ++i) x[i] = cp[i];
  float m = x[0];
#pragma unroll
  for (int i = 1; i < NCP1; ++i) m = fmaxf(m, x[i]);
  double S = 0.0;
#pragma unroll
  for (int i = 0; i < NCP1; ++i) S += exp((double)x[i] - (double)m);
  marr[idx] = m;
  sarr[idx] = S;
}

__device__ __forceinline__ double get_sd(const float* __restrict__ conf,
                                         const float* __restrict__ marr,
                                         const double* __restrict__ sarr,
                                         size_t ba, int c) {
  const float* cp = conf + ba * NCP1;
  float m;
  double S;
  if (sarr) {
    m = marr[ba];
    S = sarr[ba];
  } else {
    m = cp[0];
    for (int i = 1; i < NCP1; ++i) m = fmaxf(m, cp[i]);
    S = 0.0;
    for (int i = 0; i < NCP1; ++i) S += exp((double)cp[i] - (double)m);
  }
  return exp((double)cp[c + 1] - (double)m) / S;
}

__global__ __launch_bounds__(256) void select_nms_kernel(
    const float* __restrict__ conf, const float* __restrict__ marr,
    const double* __restrict__ sarr, const float* __restrict__ loc,
    const float* __restrict__ anchor, float* __restrict__ out) {
  __shared__ __align__(16) unsigned short s16[A];
  __shared__ unsigned hist[256];
  __shared__ unsigned scan0[256];
  __shared__ unsigned long long cand[512];
  __shared__ unsigned sh_cnt, sh_selbin, sh_need, sh_ctot;

  double* cbd = (double*)s16;
  double* ar = cbd + K * 4;
  unsigned* rows = (unsigned*)(ar + K);
  unsigned* kp = rows + K * 8;

  int tid = threadIdx.x;
  int bc = blockIdx.x;
  int b = bc / NC, c = bc % NC;
  size_t base = (size_t)b << ABITS;

  for (int a = tid; a < A; a += 256) {
    double sd = get_sd(conf, marr, sarr, base + a, c);
    unsigned short key = 0;
    if (sd >= TH_CONF) {
      float f = (float)sd;
      key = (unsigned short)(__float_as_uint(f) >> 16);
    }
    s16[a] = key;
  }
  __syncthreads();

  unsigned need = K, pfx = 0;
  bool smallcase = false;
  for (int p = 0; p < 2; ++p) {
    hist[tid] = 0;
    __syncthreads();
    for (int a = tid; a < A; a += 256) {
      unsigned v = s16[a];
      if (v && (p == 0 || (v >> 8) == pfx))
        atomicAdd(&hist[(p == 0) ? (v >> 8) : (v & 0xFFu)], 1u);
    }
    __syncthreads();
    scan0[tid] = hist[tid];
    __syncthreads();
    for (int st = 1; st < 256; st <<= 1) {
      unsigned mine = scan0[tid];
      unsigned oth = (tid + st < 256) ? scan0[tid + st] : 0u;
      __syncthreads();
      scan0[tid] = mine + oth;
      __syncthreads();
    }
    if (p == 0) {
      if (tid == 0) sh_ctot = scan0[0];
      __syncthreads();
      if (sh_ctot <= (unsigned)K) { smallcase = true; break; }
    }
    unsigned nxt = (tid == 255) ? 0u : scan0[tid + 1];
    if (scan0[tid] >= need && nxt < need) { sh_selbin = tid; sh_need = need - nxt; }
    __syncthreads();
    pfx = (pfx << 8) | sh_selbin;
    need = sh_need;
    __syncthreads();
  }
  unsigned pivot16 = smallcase ? 0x3D4Cu : pfx;

  if (tid == 0) sh_cnt = 0;
  __syncthreads();
  for (int a = tid; a < A; a += 256) {
    double sd = get_sd(conf, marr, sarr, base + a, c);
    if (sd >= TH_CONF) {
      float f = (float)sd;
      if ((__float_as_uint(f) >> 16) >= pivot16) {
        unsigned pos = atomicAdd(&sh_cnt, 1u);
        if (pos < 512) {
          unsigned long long db = (unsigned long long)__double_as_longlong(sd);
          cand[pos] = (db & 0xFFFFFFFFFFFF0000ull) |
                      (unsigned long long)(65535u - (unsigned)a);
        }
      }
    }
  }
  __syncthreads();
  unsigned ccount = sh_cnt < 512u ? sh_cnt : 512u;
  unsigned Ct = ccount < (unsigned)K ? ccount : (unsigned)K;
  for (int i = tid; i < 512; i += 256)
    if ((unsigned)i >= ccount) cand[i] = 0ull;
  __syncthreads();

  for (unsigned k2 = 2; k2 <= 512; k2 <<= 1) {
    for (unsigned j = k2 >> 1; j > 0; j >>= 1) {
      for (unsigned i = tid; i < 512; i += 256) {
        unsigned ixj = i ^ j;
        if (ixj > i) {
          unsigned long long va = cand[i], vb = cand[ixj];
          bool desc = ((i & k2) == 0);
          if (desc ? (va < vb) : (va > vb)) { cand[i] = vb; cand[ixj] = va; }
        }
      }
      __syncthreads();
    }
  }

  if ((unsigned)tid < Ct) {
    unsigned a = 65535u - (unsigned)(cand[tid] & 0xFFFFull);
    double o[4];
    decode_d(loc, anchor, base + a, a, o);
    cbd[tid * 4 + 0] = o[0]; cbd[tid * 4 + 1] = o[1];
    cbd[tid * 4 + 2] = o[2]; cbd[tid * 4 + 3] = o[3];
    ar[tid] = (o[2] - o[0]) * (o[3] - o[1]);
  }
  __syncthreads();

  for (int id = tid; id < (int)Ct * 8; id += 256) {
    int i = id >> 3, w = id & 7;
    double xi0 = cbd[i * 4 + 0], yi0 = cbd[i * 4 + 1];
    double xi1 = cbd[i * 4 + 2], yi1 = cbd[i * 4 + 3];
    double ai = ar[i];
    unsigned bits = 0;
    int j0 = w * 32;
    for (int jj = 0; jj < 32; ++jj) {
      int j = j0 + jj;
      if (j < (int)Ct) {
        double ltx = fmax(xi0, cbd[j * 4 + 0]);
        double lty = fmax(yi0, cbd[j * 4 + 1]);
        double rbx = fmin(xi1, cbd[j * 4 + 2]);
        double rby = fmin(yi1, cbd[j * 4 + 3]);
        double iw = fmax(rbx - ltx, 0.0);
        double ih = fmax(rby - lty, 0.0);
        double inter = iw * ih;
        double iou = inter / (ai + ar[j] - inter + 1e-9);
        if (iou > TH_IOU) bits |= (1u << jj);
      }
    }
    rows[i * 8 + w] = bits;
  }
  __syncthreads();

  if (tid < 64) {
    unsigned supp = 0;
    for (int i = 0; i < (int)Ct; ++i) {
      unsigned wsrc = __shfl(supp, i >> 5);
      bool kkeep = ((wsrc >> (i & 31)) & 1u) == 0u;
      if (tid == 0) kp[i] = kkeep ? 1u : 0u;
      unsigned rw = (tid < 8) ? rows[i * 8 + tid] : 0u;
      if (kkeep) supp |= rw;
    }
  }
  __syncthreads();

  if (tid < K) {
    bool kkeep = ((unsigned)tid < Ct) && (kp[tid] != 0u);
    float o0 = 0.f, o1 = 0.f, o2 = 0.f, o3 = 0.f, o4 = 0.f;
    if (kkeep) {
      o0 = (float)cbd[tid * 4 + 0]; o1 = (float)cbd[tid * 4 + 1];
      o2 = (float)cbd[tid * 4 + 2]; o3 = (float)cbd[tid * 4 + 3];
      double sd = __longlong_as_double(
          (long long)(cand[tid] & 0xFFFFFFFFFFFF0000ull));
      o4 = (float)sd;
    }
    size_t ob = ((size_t)bc * K + tid) * 5;
    out[ob + 0] = o0; out[ob + 1] = o1; out[ob + 2] = o2;
    out[ob + 3] = o3; out[ob + 4] = o4;
    out[(size_t)B * NC * K * 5 + (size_t)bc * K + tid] = kkeep ? 1.f : 0.f;
  }
}

extern "C" void kernel_launch(void* const* d_in, const int* in_sizes, int n_in,
                              void* d_out, int out_size, void* d_ws, size_t ws_size,
                              hipStream_t stream) {
  (void)in_sizes; (void)n_in; (void)out_size;
  const float* conf = (const float*)d_in[0];
  const float* loc = (const float*)d_in[1];
  const float* anchor = (const float*)d_in[2];
  float* out = (float*)d_out;

  size_t nBA = (size_t)B * A;
  size_t need_fast = nBA * sizeof(double) + nBA * sizeof(float) +
                     nBA * NC * sizeof(unsigned short);      // 52 MB
  size_t need_mid = nBA * (sizeof(float) + sizeof(double));  // 12 MB

  if (ws_size >= need_fast) {
    double* sarr = (double*)d_ws;
    float* marr = (float*)(sarr + nBA);
    unsigned short* keys = (unsigned short*)(marr + nBA);
    prep_fast<<<(B * A) / 256, 256, 0, stream>>>(conf, marr, sarr, keys);
    select_fast<<<B * NC, 256, 0, stream>>>(conf, marr, sarr, loc, anchor, keys, out);
  } else if (ws_size >= need_mid) {
    float* marr = (float*)d_ws;
    double* sarr = (double*)((char*)d_ws + nBA * sizeof(float));
    prep_kernel<<<(B * A) / 256, 256, 0, stream>>>(conf, marr, sarr);
    select_nms_kernel<<<B * NC, 256, 0, stream>>>(conf, marr, sarr, loc, anchor, out);
  } else {
    select_nms_kernel<<<B * NC, 256, 0, stream>>>(conf, nullptr, nullptr, loc, anchor, out);
  }
}

// Round 5
// 116.307 us; speedup vs baseline: 5.4023x; 1.3507x over previous
//
#include <hip/hip_runtime.h>

// DetectPostProcess: softmax -> decode -> per-(b,c) top-200 -> greedy NMS.
// Decisions (ordering, top-K membership, IoU>0.5) in f64, identical to the
// round-2..4 passing kernels; 16-bit selection keys precomputed in prep.
// Round 5: select_fast at 512 threads; IoU phase remapped id=(w*Ct+i) so the
// inner j-loop LDS reads are wave-broadcast (was 8-way bank conflict); box+area
// fused into a 5-double stride (4-way on outer reads only).
// Outputs: objs [B,NC,K,5] then keep [B,NC,K] (as 0.0/1.0), flat in d_out.

constexpr int B = 32;
constexpr int A = 32768;     // power of two
constexpr int ABITS = 15;    // log2(A)
constexpr int NCP1 = 21;
constexpr int NC = 20;
constexpr int K = 200;

#define TH_CONF 0.05
#define TH_IOU  0.5

// ============================ FAST PATH =====================================
// prep_fast: per (b,a): m (f32 max), S (f64 sum), and 20 transposed u16 keys.
__global__ __launch_bounds__(256) void prep_fast(
    const float* __restrict__ conf, float* __restrict__ marr,
    double* __restrict__ sarr, unsigned short* __restrict__ keys) {
  int idx = blockIdx.x * 256 + threadIdx.x;   // 0 .. B*A-1
  int b = idx >> ABITS;
  int a = idx & (A - 1);
  const float* cp = conf + (size_t)idx * NCP1;
  float x[NCP1];
#pragma unroll
  for (int i = 0; i < NCP1; ++i) x[i] = cp[i];
  float m = x[0];
#pragma unroll
  for (int i = 1; i < NCP1; ++i) m = fmaxf(m, x[i]);
  double e[NCP1];
  double S = 0.0;
#pragma unroll
  for (int i = 0; i < NCP1; ++i) {
    e[i] = exp((double)x[i] - (double)m);
    S += e[i];
  }
  marr[idx] = m;
  sarr[idx] = S;
  double rs = 1.0 / S;
  size_t kbase = ((size_t)(b * NC) << ABITS) + a;
#pragma unroll
  for (int c = 0; c < NC; ++c) {
    double sd = e[c + 1] * rs;                 // ~1ulp from e/S; key-grade only
    unsigned short key = 0;
    if (sd >= TH_CONF) {
      float f = (float)sd;
      key = (unsigned short)(__float_as_uint(f) >> 16);
    }
    keys[kbase + ((size_t)c << ABITS)] = key;
  }
}

// f64 box decode for one anchor.
__device__ __forceinline__ void decode_d(const float* __restrict__ loc,
                                         const float* __restrict__ anchor,
                                         size_t ba, int a, double* o) {
  const float* lp = loc + ba * 4;
  const float* ap = anchor + (size_t)a * 4;
  double l0 = lp[0], l1 = lp[1], l2 = lp[2], l3 = lp[3];
  double cx = ap[0], cy = ap[1], aw = ap[2], ah = ap[3];
  double X = (l0 * 0.125) * aw + cx;
  double Y = (l1 * 0.125) * ah + cy;
  double bw = exp(l2 * 0.125) * aw;
  double bh = exp(l3 * 0.125) * ah;
  o[0] = X - bw * 0.5;
  o[1] = Y - bh * 0.5;
  o[2] = X + bw * 0.5;
  o[3] = Y + bh * 0.5;
}

// select_fast: single-pass pivot histogram + vectorized collect; exact f64 for
// candidates only; sort + IoU + greedy scan (decision-identical to round 2).
__global__ __launch_bounds__(512) void select_fast(
    const float* __restrict__ conf, const float* __restrict__ marr,
    const double* __restrict__ sarr, const float* __restrict__ loc,
    const float* __restrict__ anchor, const unsigned short* __restrict__ keys,
    float* __restrict__ out) {
  constexpr int NBIN = 1024;
  constexpr unsigned KBASE = 0x3D4Cu;   // bits(0.05f) >> 16; min nonzero key
  constexpr int NT = 512;

  __shared__ unsigned hist[NBIN];
  __shared__ unsigned wsum[NT];
  __shared__ unsigned long long cand[512];
  __shared__ int clist[512];
  __shared__ double cbd5[K * 5];        // x0,y0,x1,y1,area per box (stride 5)
  __shared__ unsigned rows[K * 8];
  __shared__ unsigned kp[K];
  __shared__ unsigned sh_cnt, sh_selbin, sh_total;

  int tid = threadIdx.x;
  int bc = blockIdx.x;
  int b = bc / NC, c = bc % NC;
  size_t base = (size_t)b << ABITS;
  const unsigned short* krow = keys + ((size_t)bc << ABITS);
  const uint4* kv = (const uint4*)krow;     // A/8 vec entries (8 keys each)

  // ---- 1. one-pass histogram over compressed key range ----
  for (int i = tid; i < NBIN; i += NT) hist[i] = 0;
  if (tid == 0) sh_cnt = 0;
  __syncthreads();
  for (int i = tid; i < A / 8; i += NT) {
    uint4 v = kv[i];
    unsigned w[4] = {v.x, v.y, v.z, v.w};
#pragma unroll
    for (int q = 0; q < 4; ++q) {
      unsigned lo = w[q] & 0xFFFFu, hi = w[q] >> 16;
      if (lo) atomicAdd(&hist[min(lo - KBASE, (unsigned)(NBIN - 1))], 1u);
      if (hi) atomicAdd(&hist[min(hi - KBASE, (unsigned)(NBIN - 1))], 1u);
    }
  }
  __syncthreads();

  // ---- 2. suffix scan (cnt_ge) + exact 16-bit pivot ----
  unsigned h0 = hist[tid * 2 + 0], h1 = hist[tid * 2 + 1];
  wsum[tid] = h0 + h1;
  __syncthreads();
  for (int st = 1; st < NT; st <<= 1) {   // inclusive suffix sum over threads
    unsigned mine = wsum[tid];
    unsigned oth = (tid + st < NT) ? wsum[tid + st] : 0u;
    __syncthreads();
    wsum[tid] = mine + oth;
    __syncthreads();
  }
  unsigned above = (tid < NT - 1) ? wsum[tid + 1] : 0u;  // cnt_ge at bin 2*(tid+1)
  if (tid == 0) sh_total = wsum[0];
  unsigned cg1 = h1 + above;
  unsigned cg0 = h0 + cg1;
  if (cg1 >= (unsigned)K && above < (unsigned)K) sh_selbin = tid * 2 + 1;
  if (cg0 >= (unsigned)K && cg1 < (unsigned)K) sh_selbin = tid * 2 + 0;
  __syncthreads();
  unsigned pivot16 = (sh_total <= (unsigned)K) ? KBASE : (KBASE + sh_selbin);

  // ---- 3. collect candidate anchor ids (superset of true top-K) ----
  for (int i = tid; i < A / 8; i += NT) {
    uint4 v = kv[i];
    unsigned w[4] = {v.x, v.y, v.z, v.w};
#pragma unroll
    for (int q = 0; q < 4; ++q) {
      unsigned lo = w[q] & 0xFFFFu, hi = w[q] >> 16;
      if (lo >= pivot16) {
        unsigned pos = atomicAdd(&sh_cnt, 1u);
        if (pos < 512) clist[pos] = i * 8 + q * 2 + 0;
      }
      if (hi >= pivot16) {
        unsigned pos = atomicAdd(&sh_cnt, 1u);
        if (pos < 512) clist[pos] = i * 8 + q * 2 + 1;
      }
    }
  }
  __syncthreads();
  unsigned ccount = sh_cnt < 512u ? sh_cnt : 512u;
  unsigned Ct = ccount < (unsigned)K ? ccount : (unsigned)K;

  // ---- 4. exact f64 scores for candidates; build sort keys ----
  for (int i = tid; i < 512; i += NT) {
    unsigned long long key = 0ull;
    if ((unsigned)i < ccount) {
      int a = clist[i];
      size_t ba = base + a;
      double sd = exp((double)conf[ba * NCP1 + (c + 1)] - (double)marr[ba]) / sarr[ba];
      if (sd >= TH_CONF) {
        unsigned long long db = (unsigned long long)__double_as_longlong(sd);
        key = (db & 0xFFFFFFFFFFFF0000ull) |
              (unsigned long long)(65535u - (unsigned)a);
      }
    }
    cand[i] = key;
  }
  __syncthreads();

  // ---- 5. bitonic sort (adaptive 256/512) desc: (score bits desc, idx asc) ----
  unsigned n2 = (ccount <= 256u) ? 256u : 512u;
  for (unsigned k2 = 2; k2 <= n2; k2 <<= 1) {
    for (unsigned j = k2 >> 1; j > 0; j >>= 1) {
      for (unsigned i = tid; i < n2; i += NT) {
        unsigned ixj = i ^ j;
        if (ixj > i) {
          unsigned long long va = cand[i], vb = cand[ixj];
          bool desc = ((i & k2) == 0);
          if (desc ? (va < vb) : (va > vb)) { cand[i] = vb; cand[ixj] = va; }
        }
      }
      __syncthreads();
    }
  }

  // ---- 6. decode candidate boxes (f64) ----
  if ((unsigned)tid < Ct) {
    unsigned long long key = cand[tid];
    bool valid = (key >> 16) != 0ull;
    double o[4] = {0.0, 0.0, 0.0, 0.0};
    double aa = 0.0;
    if (valid) {
      unsigned a = (65535u - (unsigned)(key & 0xFFFFull)) & (A - 1);
      decode_d(loc, anchor, base + a, a, o);
      aa = (o[2] - o[0]) * (o[3] - o[1]);
    }
    cbd5[tid * 5 + 0] = o[0]; cbd5[tid * 5 + 1] = o[1];
    cbd5[tid * 5 + 2] = o[2]; cbd5[tid * 5 + 3] = o[3];
    cbd5[tid * 5 + 4] = aa;
  }
  __syncthreads();

  // ---- 7. IoU bitmask rows: id = w*Ct + i so inner reads are broadcast ----
  int total_iw = (int)Ct * 8;
  for (int id = tid; id < total_iw; id += NT) {
    int i = id % (int)Ct;
    int w = id / (int)Ct;
    double xi0 = cbd5[i * 5 + 0], yi0 = cbd5[i * 5 + 1];
    double xi1 = cbd5[i * 5 + 2], yi1 = cbd5[i * 5 + 3];
    double ai = cbd5[i * 5 + 4];
    unsigned bits = 0;
    int j0 = w * 32;
    for (int jj = 0; jj < 32; ++jj) {
      int j = j0 + jj;
      if (j < (int)Ct) {
        double ltx = fmax(xi0, cbd5[j * 5 + 0]);
        double lty = fmax(yi0, cbd5[j * 5 + 1]);
        double rbx = fmin(xi1, cbd5[j * 5 + 2]);
        double rby = fmin(yi1, cbd5[j * 5 + 3]);
        double iw = fmax(rbx - ltx, 0.0);
        double ih = fmax(rby - lty, 0.0);
        double inter = iw * ih;
        double iou = inter / (ai + cbd5[j * 5 + 4] - inter + 1e-9);
        if (iou > TH_IOU) bits |= (1u << jj);
      }
    }
    rows[i * 8 + w] = bits;
  }
  __syncthreads();

  // ---- 8. greedy scan (wave 0; matches lax.scan semantics) ----
  if (tid < 64) {
    unsigned supp = 0;
    for (int i = 0; i < (int)Ct; ++i) {
      unsigned wsrc = __shfl(supp, i >> 5);
      bool kkeep = ((wsrc >> (i & 31)) & 1u) == 0u;
      if (tid == 0) kp[i] = kkeep ? 1u : 0u;
      unsigned rw = (tid < 8) ? rows[i * 8 + tid] : 0u;
      if (kkeep) supp |= rw;
    }
  }
  __syncthreads();

  // ---- 9. write objs + keep ----
  if (tid < K) {
    bool kkeep = ((unsigned)tid < Ct) && (kp[tid] != 0u) && ((cand[tid] >> 16) != 0ull);
    float o0 = 0.f, o1 = 0.f, o2 = 0.f, o3 = 0.f, o4 = 0.f;
    if (kkeep) {
      o0 = (float)cbd5[tid * 5 + 0]; o1 = (float)cbd5[tid * 5 + 1];
      o2 = (float)cbd5[tid * 5 + 2]; o3 = (float)cbd5[tid * 5 + 3];
      double sd = __longlong_as_double(
          (long long)(cand[tid] & 0xFFFFFFFFFFFF0000ull));
      o4 = (float)sd;
    }
    size_t ob = ((size_t)bc * K + tid) * 5;
    out[ob + 0] = o0; out[ob + 1] = o1; out[ob + 2] = o2;
    out[ob + 3] = o3; out[ob + 4] = o4;
    out[(size_t)B * NC * K * 5 + (size_t)bc * K + tid] = kkeep ? 1.f : 0.f;
  }
}

// ============================ FALLBACK PATH (round-2, passing) ==============
__global__ __launch_bounds__(256) void prep_kernel(
    const float* __restrict__ conf, float* __restrict__ marr,
    double* __restrict__ sarr) {
  int idx = blockIdx.x * 256 + threadIdx.x;
  const float* cp = conf + (size_t)idx * NCP1;
  float x[NCP1];
#pragma unroll
  for (int i = 0; i < NCP1; ++i) x[i] = cp[i];
  float m = x[0];
#pragma unroll
  for (int i = 1; i < NCP1; ++i) m = fmaxf(m, x[i]);
  double S = 0.0;
#pragma unroll
  for (int i = 0; i < NCP1; ++i) S += exp((double)x[i] - (double)m);
  marr[idx] = m;
  sarr[idx] = S;
}

__device__ __forceinline__ double get_sd(const float* __restrict__ conf,
                                         const float* __restrict__ marr,
                                         const double* __restrict__ sarr,
                                         size_t ba, int c) {
  const float* cp = conf + ba * NCP1;
  float m;
  double S;
  if (sarr) {
    m = marr[ba];
    S = sarr[ba];
  } else {
    m = cp[0];
    for (int i = 1; i < NCP1; ++i) m = fmaxf(m, cp[i]);
    S = 0.0;
    for (int i = 0; i < NCP1; ++i) S += exp((double)cp[i] - (double)m);
  }
  return exp((double)cp[c + 1] - (double)m) / S;
}

__global__ __launch_bounds__(256) void select_nms_kernel(
    const float* __restrict__ conf, const float* __restrict__ marr,
    const double* __restrict__ sarr, const float* __restrict__ loc,
    const float* __restrict__ anchor, float* __restrict__ out) {
  __shared__ __align__(16) unsigned short s16[A];
  __shared__ unsigned hist[256];
  __shared__ unsigned scan0[256];
  __shared__ unsigned long long cand[512];
  __shared__ unsigned sh_cnt, sh_selbin, sh_need, sh_ctot;

  double* cbd = (double*)s16;
  double* ar = cbd + K * 4;
  unsigned* rows = (unsigned*)(ar + K);
  unsigned* kp = rows + K * 8;

  int tid = threadIdx.x;
  int bc = blockIdx.x;
  int b = bc / NC, c = bc % NC;
  size_t base = (size_t)b << ABITS;

  for (int a = tid; a < A; a += 256) {
    double sd = get_sd(conf, marr, sarr, base + a, c);
    unsigned short key = 0;
    if (sd >= TH_CONF) {
      float f = (float)sd;
      key = (unsigned short)(__float_as_uint(f) >> 16);
    }
    s16[a] = key;
  }
  __syncthreads();

  unsigned need = K, pfx = 0;
  bool smallcase = false;
  for (int p = 0; p < 2; ++p) {
    hist[tid] = 0;
    __syncthreads();
    for (int a = tid; a < A; a += 256) {
      unsigned v = s16[a];
      if (v && (p == 0 || (v >> 8) == pfx))
        atomicAdd(&hist[(p == 0) ? (v >> 8) : (v & 0xFFu)], 1u);
    }
    __syncthreads();
    scan0[tid] = hist[tid];
    __syncthreads();
    for (int st = 1; st < 256; st <<= 1) {
      unsigned mine = scan0[tid];
      unsigned oth = (tid + st < 256) ? scan0[tid + st] : 0u;
      __syncthreads();
      scan0[tid] = mine + oth;
      __syncthreads();
    }
    if (p == 0) {
      if (tid == 0) sh_ctot = scan0[0];
      __syncthreads();
      if (sh_ctot <= (unsigned)K) { smallcase = true; break; }
    }
    unsigned nxt = (tid == 255) ? 0u : scan0[tid + 1];
    if (scan0[tid] >= need && nxt < need) { sh_selbin = tid; sh_need = need - nxt; }
    __syncthreads();
    pfx = (pfx << 8) | sh_selbin;
    need = sh_need;
    __syncthreads();
  }
  unsigned pivot16 = smallcase ? 0x3D4Cu : pfx;

  if (tid == 0) sh_cnt = 0;
  __syncthreads();
  for (int a = tid; a < A; a += 256) {
    double sd = get_sd(conf, marr, sarr, base + a, c);
    if (sd >= TH_CONF) {
      float f = (float)sd;
      if ((__float_as_uint(f) >> 16) >= pivot16) {
        unsigned pos = atomicAdd(&sh_cnt, 1u);
        if (pos < 512) {
          unsigned long long db = (unsigned long long)__double_as_longlong(sd);
          cand[pos] = (db & 0xFFFFFFFFFFFF0000ull) |
                      (unsigned long long)(65535u - (unsigned)a);
        }
      }
    }
  }
  __syncthreads();
  unsigned ccount = sh_cnt < 512u ? sh_cnt : 512u;
  unsigned Ct = ccount < (unsigned)K ? ccount : (unsigned)K;
  for (int i = tid; i < 512; i += 256)
    if ((unsigned)i >= ccount) cand[i] = 0ull;
  __syncthreads();

  for (unsigned k2 = 2; k2 <= 512; k2 <<= 1) {
    for (unsigned j = k2 >> 1; j > 0; j >>= 1) {
      for (unsigned i = tid; i < 512; i += 256) {
        unsigned ixj = i ^ j;
        if (ixj > i) {
          unsigned long long va = cand[i], vb = cand[ixj];
          bool desc = ((i & k2) == 0);
          if (desc ? (va < vb) : (va > vb)) { cand[i] = vb; cand[ixj] = va; }
        }
      }
      __syncthreads();
    }
  }

  if ((unsigned)tid < Ct) {
    unsigned a = 65535u - (unsigned)(cand[tid] & 0xFFFFull);
    double o[4];
    decode_d(loc, anchor, base + a, a, o);
    cbd[tid * 4 + 0] = o[0]; cbd[tid * 4 + 1] = o[1];
    cbd[tid * 4 + 2] = o[2]; cbd[tid * 4 + 3] = o[3];
    ar[tid] = (o[2] - o[0]) * (o[3] - o[1]);
  }
  __syncthreads();

  for (int id = tid; id < (int)Ct * 8; id += 256) {
    int i = id >> 3, w = id & 7;
    double xi0 = cbd[i * 4 + 0], yi0 = cbd[i * 4 + 1];
    double xi1 = cbd[i * 4 + 2], yi1 = cbd[i * 4 + 3];
    double ai = ar[i];
    unsigned bits = 0;
    int j0 = w * 32;
    for (int jj = 0; jj < 32; ++jj) {
      int j = j0 + jj;
      if (j < (int)Ct) {
        double ltx = fmax(xi0, cbd[j * 4 + 0]);
        double lty = fmax(yi0, cbd[j * 4 + 1]);
        double rbx = fmin(xi1, cbd[j * 4 + 2]);
        double rby = fmin(yi1, cbd[j * 4 + 3]);
        double iw = fmax(rbx - ltx, 0.0);
        double ih = fmax(rby - lty, 0.0);
        double inter = iw * ih;
        double iou = inter / (ai + ar[j] - inter + 1e-9);
        if (iou > TH_IOU) bits |= (1u << jj);
      }
    }
    rows[i * 8 + w] = bits;
  }
  __syncthreads();

  if (tid < 64) {
    unsigned supp = 0;
    for (int i = 0; i < (int)Ct; ++i) {
      unsigned wsrc = __shfl(supp, i >> 5);
      bool kkeep = ((wsrc >> (i & 31)) & 1u) == 0u;
      if (tid == 0) kp[i] = kkeep ? 1u : 0u;
      unsigned rw = (tid < 8) ? rows[i * 8 + tid] : 0u;
      if (kkeep) supp |= rw;
    }
  }
  __syncthreads();

  if (tid < K) {
    bool kkeep = ((unsigned)tid < Ct) && (kp[tid] != 0u);
    float o0 = 0.f, o1 = 0.f, o2 = 0.f, o3 = 0.f, o4 = 0.f;
    if (kkeep) {
      o0 = (float)cbd[tid * 4 + 0]; o1 = (float)cbd[tid * 4 + 1];
      o2 = (float)cbd[tid * 4 + 2]; o3 = (float)cbd[tid * 4 + 3];
      double sd = __longlong_as_double(
          (long long)(cand[tid] & 0xFFFFFFFFFFFF0000ull));
      o4 = (float)sd;
    }
    size_t ob = ((size_t)bc * K + tid) * 5;
    out[ob + 0] = o0; out[ob + 1] = o1; out[ob + 2] = o2;
    out[ob + 3] = o3; out[ob + 4] = o4;
    out[(size_t)B * NC * K * 5 + (size_t)bc * K + tid] = kkeep ? 1.f : 0.f;
  }
}

extern "C" void kernel_launch(void* const* d_in, const int* in_sizes, int n_in,
                              void* d_out, int out_size, void* d_ws, size_t ws_size,
                              hipStream_t stream) {
  (void)in_sizes; (void)n_in; (void)out_size;
  const float* conf = (const float*)d_in[0];
  const float* loc = (const float*)d_in[1];
  const float* anchor = (const float*)d_in[2];
  float* out = (float*)d_out;

  size_t nBA = (size_t)B * A;
  size_t need_fast = nBA * sizeof(double) + nBA * sizeof(float) +
                     nBA * NC * sizeof(unsigned short);      // 52 MB
  size_t need_mid = nBA * (sizeof(float) + sizeof(double));  // 12 MB

  if (ws_size >= need_fast) {
    double* sarr = (double*)d_ws;
    float* marr = (float*)(sarr + nBA);
    unsigned short* keys = (unsigned short*)(marr + nBA);
    prep_fast<<<(B * A) / 256, 256, 0, stream>>>(conf, marr, sarr, keys);
    select_fast<<<B * NC, 512, 0, stream>>>(conf, marr, sarr, loc, anchor, keys, out);
  } else if (ws_size >= need_mid) {
    float* marr = (float*)d_ws;
    double* sarr = (double*)((char*)d_ws + nBA * sizeof(float));
    prep_kernel<<<(B * A) / 256, 256, 0, stream>>>(conf, marr, sarr);
    select_nms_kernel<<<B * NC, 256, 0, stream>>>(conf, marr, sarr, loc, anchor, out);
  } else {
    select_nms_kernel<<<B * NC, 256, 0, stream>>>(conf, nullptr, nullptr, loc, anchor, out);
  }
}

// Round 6
// 110.498 us; speedup vs baseline: 5.6863x; 1.0526x over previous
//
#include <hip/hip_runtime.h>

// DetectPostProcess: softmax -> decode -> per-(b,c) top-200 -> greedy NMS.
// Decisions (ordering, top-K membership, IoU>0.5) in f64, identical to the
// round-2..5 passing kernels.
// Round 6: histogram hoisted to a high-occupancy prehist kernel (global
// 576-bin exact histograms per (b,c)); shfl-based suffix scan and bitonic
// (fewer barriers); division-free IoU compare.
// Outputs: objs [B,NC,K,5] then keep [B,NC,K] (as 0.0/1.0), flat in d_out.

constexpr int B = 32;
constexpr int A = 32768;     // power of two
constexpr int ABITS = 15;    // log2(A)
constexpr int NCP1 = 21;
constexpr int NC = 20;
constexpr int K = 200;
constexpr int NBIN = 576;    // key range 0x3D4C..0x3F80 = 564 values
#define KBASE 0x3D4Cu        // bits(0.05f) >> 16; min nonzero key

#define TH_CONF 0.05
#define TH_IOU  0.5

// ============================ FAST PATH =====================================
// prep_fast: per (b,a): m (f32 max), S (f64 sum), and 20 transposed u16 keys.
__global__ __launch_bounds__(256) void prep_fast(
    const float* __restrict__ conf, float* __restrict__ marr,
    double* __restrict__ sarr, unsigned short* __restrict__ keys) {
  int idx = blockIdx.x * 256 + threadIdx.x;   // 0 .. B*A-1
  int b = idx >> ABITS;
  int a = idx & (A - 1);
  const float* cp = conf + (size_t)idx * NCP1;
  float x[NCP1];
#pragma unroll
  for (int i = 0; i < NCP1; ++i) x[i] = cp[i];
  float m = x[0];
#pragma unroll
  for (int i = 1; i < NCP1; ++i) m = fmaxf(m, x[i]);
  double e[NCP1];
  double S = 0.0;
#pragma unroll
  for (int i = 0; i < NCP1; ++i) {
    e[i] = exp((double)x[i] - (double)m);
    S += e[i];
  }
  marr[idx] = m;
  sarr[idx] = S;
  double rs = 1.0 / S;
  size_t kbase = ((size_t)(b * NC) << ABITS) + a;
#pragma unroll
  for (int c = 0; c < NC; ++c) {
    double sd = e[c + 1] * rs;                 // ~1ulp from e/S; key-grade only
    unsigned short key = 0;
    if (sd >= TH_CONF) {
      float f = (float)sd;
      key = (unsigned short)(__float_as_uint(f) >> 16);
    }
    keys[kbase + ((size_t)c << ABITS)] = key;
  }
}

// prehist: 4 blocks per (b,c); LDS-aggregated 576-bin histogram -> global.
__global__ __launch_bounds__(256) void prehist_kernel(
    const unsigned short* __restrict__ keys, unsigned* __restrict__ ghist) {
  __shared__ unsigned h[NBIN];
  int tid = threadIdx.x;
  int blk = blockIdx.x;          // 0..B*NC*4-1
  int bc = blk >> 2, chunk = blk & 3;
  for (int i = tid; i < NBIN; i += 256) h[i] = 0;
  __syncthreads();
  const uint4* kv = (const uint4*)(keys + ((size_t)bc << ABITS) + chunk * (A / 4));
  for (int i = tid; i < A / 4 / 8; i += 256) {   // 1024 uint4s
    uint4 v = kv[i];
    unsigned w[4] = {v.x, v.y, v.z, v.w};
#pragma unroll
    for (int q = 0; q < 4; ++q) {
      unsigned lo = w[q] & 0xFFFFu, hi = w[q] >> 16;
      if (lo) atomicAdd(&h[min(lo - KBASE, (unsigned)(NBIN - 1))], 1u);
      if (hi) atomicAdd(&h[min(hi - KBASE, (unsigned)(NBIN - 1))], 1u);
    }
  }
  __syncthreads();
  unsigned* grow = ghist + (size_t)bc * NBIN;
  for (int i = tid; i < NBIN; i += 256) {
    unsigned cnt = h[i];
    if (cnt) atomicAdd(&grow[i], cnt);
  }
}

// f64 box decode for one anchor.
__device__ __forceinline__ void decode_d(const float* __restrict__ loc,
                                         const float* __restrict__ anchor,
                                         size_t ba, int a, double* o) {
  const float* lp = loc + ba * 4;
  const float* ap = anchor + (size_t)a * 4;
  double l0 = lp[0], l1 = lp[1], l2 = lp[2], l3 = lp[3];
  double cx = ap[0], cy = ap[1], aw = ap[2], ah = ap[3];
  double X = (l0 * 0.125) * aw + cx;
  double Y = (l1 * 0.125) * ah + cy;
  double bw = exp(l2 * 0.125) * aw;
  double bh = exp(l3 * 0.125) * ah;
  o[0] = X - bw * 0.5;
  o[1] = Y - bh * 0.5;
  o[2] = X + bw * 0.5;
  o[3] = Y + bh * 0.5;
}

// select_fast: pivot from ghist (or in-kernel hist if ghist==null), collect,
// exact f64 rescoring, shfl-bitonic sort, div-free IoU, greedy scan.
__global__ __launch_bounds__(512) void select_fast(
    const float* __restrict__ conf, const float* __restrict__ marr,
    const double* __restrict__ sarr, const float* __restrict__ loc,
    const float* __restrict__ anchor, const unsigned short* __restrict__ keys,
    const unsigned* __restrict__ ghist, float* __restrict__ out) {
  constexpr int NT = 512;

  __shared__ unsigned hist[NBIN];       // fallback-path histogram
  __shared__ unsigned wtot[8], wsuf[8];
  __shared__ unsigned long long cand[512];
  __shared__ int clist[512];
  __shared__ double cbd5[K * 5];        // x0,y0,x1,y1,area per box (stride 5)
  __shared__ unsigned rows[K * 8];
  __shared__ unsigned kp[K];
  __shared__ unsigned sh_cnt, sh_selbin, sh_total;

  int tid = threadIdx.x;
  unsigned lane = tid & 63, wid = tid >> 6;
  int bc = blockIdx.x;
  int b = bc / NC, c = bc % NC;
  size_t base = (size_t)b << ABITS;
  const unsigned short* krow = keys + ((size_t)bc << ABITS);
  const uint4* kv = (const uint4*)krow;     // A/8 vec entries (8 keys each)

  if (tid == 0) sh_cnt = 0;

  // ---- 1. per-bin counts h0,h1 for bins 2*tid, 2*tid+1 ----
  unsigned h0 = 0, h1 = 0;
  if (ghist) {
    if (tid < NBIN / 2) {
      uint2 hh = ((const uint2*)(ghist + (size_t)bc * NBIN))[tid];
      h0 = hh.x; h1 = hh.y;
    }
  } else {
    for (int i = tid; i < NBIN; i += NT) hist[i] = 0;
    __syncthreads();
    for (int i = tid; i < A / 8; i += NT) {
      uint4 v = kv[i];
      unsigned w[4] = {v.x, v.y, v.z, v.w};
#pragma unroll
      for (int q = 0; q < 4; ++q) {
        unsigned lo = w[q] & 0xFFFFu, hi = w[q] >> 16;
        if (lo) atomicAdd(&hist[min(lo - KBASE, (unsigned)(NBIN - 1))], 1u);
        if (hi) atomicAdd(&hist[min(hi - KBASE, (unsigned)(NBIN - 1))], 1u);
      }
    }
    __syncthreads();
    if (tid < NBIN / 2) { h0 = hist[2 * tid]; h1 = hist[2 * tid + 1]; }
  }

  // ---- 2. shfl suffix scan (cnt_ge) + exact 16-bit pivot ----
  unsigned s = h0 + h1;
  unsigned S = s;
#pragma unroll
  for (int d = 1; d < 64; d <<= 1) {
    unsigned o = __shfl_down(S, d, 64);
    if (lane + d < 64) S += o;
  }
  if (lane == 0) wtot[wid] = S;
  __syncthreads();
  if (tid < 8) {
    unsigned acc = 0;
    for (int w2 = tid + 1; w2 < 8; ++w2) acc += wtot[w2];
    wsuf[tid] = acc;
    if (tid == 0) sh_total = acc + wtot[0];
  }
  __syncthreads();
  unsigned Sfull = S + wsuf[wid];       // suffix starting at this thread
  unsigned above2 = Sfull - s;          // suffix starting at thread tid+1
  unsigned cg1 = h1 + above2;
  unsigned cg0 = h0 + cg1;
  if (cg1 >= (unsigned)K && above2 < (unsigned)K) sh_selbin = tid * 2 + 1;
  if (cg0 >= (unsigned)K && cg1 < (unsigned)K) sh_selbin = tid * 2 + 0;
  __syncthreads();
  unsigned pivot16 = (sh_total <= (unsigned)K) ? KBASE : (KBASE + sh_selbin);

  // ---- 3. collect candidate anchor ids (superset of true top-K) ----
  for (int i = tid; i < A / 8; i += NT) {
    uint4 v = kv[i];
    unsigned w[4] = {v.x, v.y, v.z, v.w};
#pragma unroll
    for (int q = 0; q < 4; ++q) {
      unsigned lo = w[q] & 0xFFFFu, hi = w[q] >> 16;
      if (lo >= pivot16) {
        unsigned pos = atomicAdd(&sh_cnt, 1u);
        if (pos < 512) clist[pos] = i * 8 + q * 2 + 0;
      }
      if (hi >= pivot16) {
        unsigned pos = atomicAdd(&sh_cnt, 1u);
        if (pos < 512) clist[pos] = i * 8 + q * 2 + 1;
      }
    }
  }
  __syncthreads();
  unsigned ccount = sh_cnt < 512u ? sh_cnt : 512u;
  unsigned Ct = ccount < (unsigned)K ? ccount : (unsigned)K;

  // ---- 4. exact f64 scores for candidates; build sort keys ----
  for (int i = tid; i < 512; i += NT) {
    unsigned long long key = 0ull;
    if ((unsigned)i < ccount) {
      int a = clist[i];
      size_t ba = base + a;
      double sd = exp((double)conf[ba * NCP1 + (c + 1)] - (double)marr[ba]) / sarr[ba];
      if (sd >= TH_CONF) {
        unsigned long long db = (unsigned long long)__double_as_longlong(sd);
        key = (db & 0xFFFFFFFFFFFF0000ull) |
              (unsigned long long)(65535u - (unsigned)a);
      }
    }
    cand[i] = key;
  }
  __syncthreads();

  // ---- 5. bitonic sort desc (shfl for j<64): (score bits desc, idx asc) ----
  unsigned n2 = (ccount <= 256u) ? 256u : 512u;
  unsigned long long v = ((unsigned)tid < n2) ? cand[tid] : 0ull;
  for (unsigned k2 = 2; k2 <= n2; k2 <<= 1) {
    for (unsigned j = k2 >> 1; j > 0; j >>= 1) {
      unsigned long long p;
      if (j >= 64) {
        __syncthreads();
        if ((unsigned)tid < n2) cand[tid] = v;
        __syncthreads();
        p = ((unsigned)tid < n2) ? cand[tid ^ j] : 0ull;
      } else {
        p = __shfl_xor(v, (int)j, 64);
      }
      if ((unsigned)tid < n2) {
        bool desc = ((tid & (int)k2) == 0);
        bool lower = ((tid & (int)j) == 0);
        bool takemax = (lower == desc);
        bool vge = (v >= p);
        v = takemax ? (vge ? v : p) : (vge ? p : v);
      }
    }
  }
  __syncthreads();
  if ((unsigned)tid < n2) cand[tid] = v;
  __syncthreads();

  // ---- 6. decode candidate boxes (f64) ----
  if ((unsigned)tid < Ct) {
    unsigned long long key = cand[tid];
    bool valid = (key >> 16) != 0ull;
    double o[4] = {0.0, 0.0, 0.0, 0.0};
    double aa = 0.0;
    if (valid) {
      unsigned a = (65535u - (unsigned)(key & 0xFFFFull)) & (A - 1);
      decode_d(loc, anchor, base + a, a, o);
      aa = (o[2] - o[0]) * (o[3] - o[1]);
    }
    cbd5[tid * 5 + 0] = o[0]; cbd5[tid * 5 + 1] = o[1];
    cbd5[tid * 5 + 2] = o[2]; cbd5[tid * 5 + 3] = o[3];
    cbd5[tid * 5 + 4] = aa;
  }
  __syncthreads();

  // ---- 7. IoU bitmask rows (id = w*Ct+i -> broadcast inner reads);
  //         division-free compare: inter/den > 0.5  <=>  inter > 0.5*den ----
  int total_iw = (int)Ct * 8;
  for (int id = tid; id < total_iw; id += NT) {
    int i = id % (int)Ct;
    int w = id / (int)Ct;
    double xi0 = cbd5[i * 5 + 0], yi0 = cbd5[i * 5 + 1];
    double xi1 = cbd5[i * 5 + 2], yi1 = cbd5[i * 5 + 3];
    double ai = cbd5[i * 5 + 4];
    unsigned bits = 0;
    int j0 = w * 32;
    for (int jj = 0; jj < 32; ++jj) {
      int j = j0 + jj;
      if (j < (int)Ct) {
        double ltx = fmax(xi0, cbd5[j * 5 + 0]);
        double lty = fmax(yi0, cbd5[j * 5 + 1]);
        double rbx = fmin(xi1, cbd5[j * 5 + 2]);
        double rby = fmin(yi1, cbd5[j * 5 + 3]);
        double iw = fmax(rbx - ltx, 0.0);
        double ih = fmax(rby - lty, 0.0);
        double inter = iw * ih;
        double den = ai + cbd5[j * 5 + 4] - inter + 1e-9;
        if (inter > 0.5 * den) bits |= (1u << jj);
      }
    }
    rows[i * 8 + w] = bits;
  }
  __syncthreads();

  // ---- 8. greedy scan (wave 0; matches lax.scan semantics) ----
  if (tid < 64) {
    unsigned supp = 0;
    for (int i = 0; i < (int)Ct; ++i) {
      unsigned wsrc = __shfl(supp, i >> 5);
      bool kkeep = ((wsrc >> (i & 31)) & 1u) == 0u;
      if (tid == 0) kp[i] = kkeep ? 1u : 0u;
      unsigned rw = (tid < 8) ? rows[i * 8 + tid] : 0u;
      if (kkeep) supp |= rw;
    }
  }
  __syncthreads();

  // ---- 9. write objs + keep ----
  if (tid < K) {
    bool kkeep = ((unsigned)tid < Ct) && (kp[tid] != 0u) && ((cand[tid] >> 16) != 0ull);
    float o0 = 0.f, o1 = 0.f, o2 = 0.f, o3 = 0.f, o4 = 0.f;
    if (kkeep) {
      o0 = (float)cbd5[tid * 5 + 0]; o1 = (float)cbd5[tid * 5 + 1];
      o2 = (float)cbd5[tid * 5 + 2]; o3 = (float)cbd5[tid * 5 + 3];
      double sd = __longlong_as_double(
          (long long)(cand[tid] & 0xFFFFFFFFFFFF0000ull));
      o4 = (float)sd;
    }
    size_t ob = ((size_t)bc * K + tid) * 5;
    out[ob + 0] = o0; out[ob + 1] = o1; out[ob + 2] = o2;
    out[ob + 3] = o3; out[ob + 4] = o4;
    out[(size_t)B * NC * K * 5 + (size_t)bc * K + tid] = kkeep ? 1.f : 0.f;
  }
}

// ============================ FALLBACK PATH (round-2, passing) ==============
__global__ __launch_bounds__(256) void prep_kernel(
    const float* __restrict__ conf, float* __restrict__ marr,
    double* __restrict__ sarr) {
  int idx = blockIdx.x * 256 + threadIdx.x;
  const float* cp = conf + (size_t)idx * NCP1;
  float x[NCP1];
#pragma unroll
  for (int i = 0; i < NCP1; ++i) x[i] = cp[i];
  float m = x[0];
#pragma unroll
  for (int i = 1; i < NCP1; ++i) m = fmaxf(m, x[i]);
  double S = 0.0;
#pragma unroll
  for (int i = 0; i < NCP1; ++i) S += exp((double)x[i] - (double)m);
  marr[idx] = m;
  sarr[idx] = S;
}

__device__ __forceinline__ double get_sd(const float* __restrict__ conf,
                                         const float* __restrict__ marr,
                                         const double* __restrict__ sarr,
                                         size_t ba, int c) {
  const float* cp = conf + ba * NCP1;
  float m;
  double S;
  if (sarr) {
    m = marr[ba];
    S = sarr[ba];
  } else {
    m = cp[0];
    for (int i = 1; i < NCP1; ++i) m = fmaxf(m, cp[i]);
    S = 0.0;
    for (int i = 0; i < NCP1; ++i) S += exp((double)cp[i] - (double)m);
  }
  return exp((double)cp[c + 1] - (double)m) / S;
}

__global__ __launch_bounds__(256) void select_nms_kernel(
    const float* __restrict__ conf, const float* __restrict__ marr,
    const double* __restrict__ sarr, const float* __restrict__ loc,
    const float* __restrict__ anchor, float* __restrict__ out) {
  __shared__ __align__(16) unsigned short s16[A];
  __shared__ unsigned hist[256];
  __shared__ unsigned scan0[256];
  __shared__ unsigned long long cand[512];
  __shared__ unsigned sh_cnt, sh_selbin, sh_need, sh_ctot;

  double* cbd = (double*)s16;
  double* ar = cbd + K * 4;
  unsigned* rows = (unsigned*)(ar + K);
  unsigned* kp = rows + K * 8;

  int tid = threadIdx.x;
  int bc = blockIdx.x;
  int b = bc / NC, c = bc % NC;
  size_t base = (size_t)b << ABITS;

  for (int a = tid; a < A; a += 256) {
    double sd = get_sd(conf, marr, sarr, base + a, c);
    unsigned short key = 0;
    if (sd >= TH_CONF) {
      float f = (float)sd;
      key = (unsigned short)(__float_as_uint(f) >> 16);
    }
    s16[a] = key;
  }
  __syncthreads();

  unsigned need = K, pfx = 0;
  bool smallcase = false;
  for (int p = 0; p < 2; ++p) {
    hist[tid] = 0;
    __syncthreads();
    for (int a = tid; a < A; a += 256) {
      unsigned v = s16[a];
      if (v && (p == 0 || (v >> 8) == pfx))
        atomicAdd(&hist[(p == 0) ? (v >> 8) : (v & 0xFFu)], 1u);
    }
    __syncthreads();
    scan0[tid] = hist[tid];
    __syncthreads();
    for (int st = 1; st < 256; st <<= 1) {
      unsigned mine = scan0[tid];
      unsigned oth = (tid + st < 256) ? scan0[tid + st] : 0u;
      __syncthreads();
      scan0[tid] = mine + oth;
      __syncthreads();
    }
    if (p == 0) {
      if (tid == 0) sh_ctot = scan0[0];
      __syncthreads();
      if (sh_ctot <= (unsigned)K) { smallcase = true; break; }
    }
    unsigned nxt = (tid == 255) ? 0u : scan0[tid + 1];
    if (scan0[tid] >= need && nxt < need) { sh_selbin = tid; sh_need = need - nxt; }
    __syncthreads();
    pfx = (pfx << 8) | sh_selbin;
    need = sh_need;
    __syncthreads();
  }
  unsigned pivot16 = smallcase ? 0x3D4Cu : pfx;

  if (tid == 0) sh_cnt = 0;
  __syncthreads();
  for (int a = tid; a < A; a += 256) {
    double sd = get_sd(conf, marr, sarr, base + a, c);
    if (sd >= TH_CONF) {
      float f = (float)sd;
      if ((__float_as_uint(f) >> 16) >= pivot16) {
        unsigned pos = atomicAdd(&sh_cnt, 1u);
        if (pos < 512) {
          unsigned long long db = (unsigned long long)__double_as_longlong(sd);
          cand[pos] = (db & 0xFFFFFFFFFFFF0000ull) |
                      (unsigned long long)(65535u - (unsigned)a);
        }
      }
    }
  }
  __syncthreads();
  unsigned ccount = sh_cnt < 512u ? sh_cnt : 512u;
  unsigned Ct = ccount < (unsigned)K ? ccount : (unsigned)K;
  for (int i = tid; i < 512; i += 256)
    if ((unsigned)i >= ccount) cand[i] = 0ull;
  __syncthreads();

  for (unsigned k2 = 2; k2 <= 512; k2 <<= 1) {
    for (unsigned j = k2 >> 1; j > 0; j >>= 1) {
      for (unsigned i = tid; i < 512; i += 256) {
        unsigned ixj = i ^ j;
        if (ixj > i) {
          unsigned long long va = cand[i], vb = cand[ixj];
          bool desc = ((i & k2) == 0);
          if (desc ? (va < vb) : (va > vb)) { cand[i] = vb; cand[ixj] = va; }
        }
      }
      __syncthreads();
    }
  }

  if ((unsigned)tid < Ct) {
    unsigned a = 65535u - (unsigned)(cand[tid] & 0xFFFFull);
    double o[4];
    decode_d(loc, anchor, base + a, a, o);
    cbd[tid * 4 + 0] = o[0]; cbd[tid * 4 + 1] = o[1];
    cbd[tid * 4 + 2] = o[2]; cbd[tid * 4 + 3] = o[3];
    ar[tid] = (o[2] - o[0]) * (o[3] - o[1]);
  }
  __syncthreads();

  for (int id = tid; id < (int)Ct * 8; id += 256) {
    int i = id >> 3, w = id & 7;
    double xi0 = cbd[i * 4 + 0], yi0 = cbd[i * 4 + 1];
    double xi1 = cbd[i * 4 + 2], yi1 = cbd[i * 4 + 3];
    double ai = ar[i];
    unsigned bits = 0;
    int j0 = w * 32;
    for (int jj = 0; jj < 32; ++jj) {
      int j = j0 + jj;
      if (j < (int)Ct) {
        double ltx = fmax(xi0, cbd[j * 4 + 0]);
        double lty = fmax(yi0, cbd[j * 4 + 1]);
        double rbx = fmin(xi1, cbd[j * 4 + 2]);
        double rby = fmin(yi1, cbd[j * 4 + 3]);
        double iw = fmax(rbx - ltx, 0.0);
        double ih = fmax(rby - lty, 0.0);
        double inter = iw * ih;
        double iou = inter / (ai + ar[j] - inter + 1e-9);
        if (iou > TH_IOU) bits |= (1u << jj);
      }
    }
    rows[i * 8 + w] = bits;
  }
  __syncthreads();

  if (tid < 64) {
    unsigned supp = 0;
    for (int i = 0; i < (int)Ct; ++i) {
      unsigned wsrc = __shfl(supp, i >> 5);
      bool kkeep = ((wsrc >> (i & 31)) & 1u) == 0u;
      if (tid == 0) kp[i] = kkeep ? 1u : 0u;
      unsigned rw = (tid < 8) ? rows[i * 8 + tid] : 0u;
      if (kkeep) supp |= rw;
    }
  }
  __syncthreads();

  if (tid < K) {
    bool kkeep = ((unsigned)tid < Ct) && (kp[tid] != 0u);
    float o0 = 0.f, o1 = 0.f, o2 = 0.f, o3 = 0.f, o4 = 0.f;
    if (kkeep) {
      o0 = (float)cbd[tid * 4 + 0]; o1 = (float)cbd[tid * 4 + 1];
      o2 = (float)cbd[tid * 4 + 2]; o3 = (float)cbd[tid * 4 + 3];
      double sd = __longlong_as_double(
          (long long)(cand[tid] & 0xFFFFFFFFFFFF0000ull));
      o4 = (float)sd;
    }
    size_t ob = ((size_t)bc * K + tid) * 5;
    out[ob + 0] = o0; out[ob + 1] = o1; out[ob + 2] = o2;
    out[ob + 3] = o3; out[ob + 4] = o4;
    out[(size_t)B * NC * K * 5 + (size_t)bc * K + tid] = kkeep ? 1.f : 0.f;
  }
}

extern "C" void kernel_launch(void* const* d_in, const int* in_sizes, int n_in,
                              void* d_out, int out_size, void* d_ws, size_t ws_size,
                              hipStream_t stream) {
  (void)in_sizes; (void)n_in; (void)out_size;
  const float* conf = (const float*)d_in[0];
  const float* loc = (const float*)d_in[1];
  const float* anchor = (const float*)d_in[2];
  float* out = (float*)d_out;

  size_t nBA = (size_t)B * A;
  size_t off_sarr = 0;
  size_t off_marr = off_sarr + nBA * sizeof(double);
  size_t off_keys = off_marr + nBA * sizeof(float);
  size_t off_ghist = off_keys + nBA * NC * sizeof(unsigned short);
  size_t ghist_bytes = (size_t)B * NC * NBIN * sizeof(unsigned);
  size_t need_fast2 = off_ghist + ghist_bytes;      // ~56 MB
  size_t need_fast = off_ghist;                     // ~54.5 MB
  size_t need_mid = nBA * (sizeof(float) + sizeof(double));  // 12 MB

  if (ws_size >= need_fast) {
    double* sarr = (double*)((char*)d_ws + off_sarr);
    float* marr = (float*)((char*)d_ws + off_marr);
    unsigned short* keys = (unsigned short*)((char*)d_ws + off_keys);
    unsigned* ghist = nullptr;
    prep_fast<<<(B * A) / 256, 256, 0, stream>>>(conf, marr, sarr, keys);
    if (ws_size >= need_fast2) {
      ghist = (unsigned*)((char*)d_ws + off_ghist);
      hipMemsetAsync(ghist, 0, ghist_bytes, stream);
      prehist_kernel<<<B * NC * 4, 256, 0, stream>>>(keys, ghist);
    }
    select_fast<<<B * NC, 512, 0, stream>>>(conf, marr, sarr, loc, anchor, keys,
                                            ghist, out);
  } else if (ws_size >= need_mid) {
    float* marr = (float*)d_ws;
    double* sarr = (double*)((char*)d_ws + nBA * sizeof(float));
    prep_kernel<<<(B * A) / 256, 256, 0, stream>>>(conf, marr, sarr);
    select_nms_kernel<<<B * NC, 256, 0, stream>>>(conf, marr, sarr, loc, anchor, out);
  } else {
    select_nms_kernel<<<B * NC, 256, 0, stream>>>(conf, nullptr, nullptr, loc, anchor, out);
  }
}